// Round 8
// baseline (248.977 us; speedup 1.0000x reference)
//
#include <hip/hip_runtime.h>
#include <hip/hip_bf16.h>
#include <math.h>

#define BB 8
#define NN 4096
#define EE 65536
#define LOG2E 1.4426950408889634f

__device__ __forceinline__ float my_erf(float x){
  float ax = fabsf(x);
  float tt = 1.f/(1.f + 0.3275911f*ax);
  float poly = ((((1.061405429f*tt - 1.453152027f)*tt + 1.421413741f)*tt
                 - 0.284496736f)*tt + 0.254829592f)*tt;
  float y = 1.f - poly*expf(-ax*ax);
  return x >= 0.f ? y : -y;
}
__device__ __forceinline__ float gelu_f(float x){ return 0.5f*x*(1.0f + my_erf(x*0.7071067811865476f)); }
__device__ __forceinline__ float ld(const void* p, long i){ return ((const float*)p)[i]; }

// merged: CSR fill (blocks [0,NF), XCD-batch-bound) + layer-0 projection+linear (blocks [NF,NF+NL))
// CSR entries are USHORT: src(12b) | type(2b)<<12 — halves scatter footprint.
__global__ __launch_bounds__(256) void k_pre(
    const void* __restrict__ nf, const void* __restrict__ pw, const void* __restrict__ pb,
    const void* __restrict__ W, const void* __restrict__ a_src, const void* __restrict__ a_dst,
    const void* __restrict__ a_edge, const void* __restrict__ eemb,
    const int* __restrict__ ei, const int* __restrict__ ety,
    float* __restrict__ h, float* __restrict__ sdot, float* __restrict__ ebt,
    int* __restrict__ cursor, unsigned short* __restrict__ csr, int b0, int nb, int NF){
  if ((int)blockIdx.x < NF){
    // ---- CSR fill: 4 edges/thread via int4; one batch per XCD ----
    int fi = (int)blockIdx.x;
    int bpb = NF / nb;
    int b, q;
    if (nb == BB){ b = fi & 7; q = fi >> 3; }
    else         { b = fi / bpb; q = fi - b*bpb; }
    int e4 = q*256 + threadIdx.x;
    const int* base = ei + (long)(b0+b)*2*EE;
    int4 s4 = ((const int4*)base)[e4];
    int4 d4 = ((const int4*)(base + EE))[e4];
    int4 t4 = ((const int4*)(ety + (long)(b0+b)*EE))[e4];
    int* cb = cursor + b*NN;
    int ss[4] = {s4.x & (NN-1), s4.y & (NN-1), s4.z & (NN-1), s4.w & (NN-1)};
    int dd[4] = {d4.x & (NN-1), d4.y & (NN-1), d4.z & (NN-1), d4.w & (NN-1)};
    int tt[4] = {t4.x, t4.y, t4.z, t4.w};
    #pragma unroll
    for (int i=0;i<4;i++){
      int ty = tt[i]; ty = (ty < 0) ? 0 : (ty > 2 ? 2 : ty);
      int p = atomicAdd(&cb[dd[i]], 1);
      if (p < 64) csr[((long)(b*NN) + dd[i])*64 + p] = (unsigned short)(ss[i] | (ty << 12));
    }
    return;
  }

  // ---- projection 22->64 + linear0 64x64 + sdot ----
  __attribute__((aligned(16))) __shared__ float wlT[64*68];
  __attribute__((aligned(16))) __shared__ float nfl[32*24];
  __attribute__((aligned(16))) __shared__ float xs[32*68];
  int t = threadIdx.x;
  int lb = (int)blockIdx.x - NF;

  if (lb == 0 && t < 48){
    int ll = t >> 4, r = t & 15;
    if (r < 12){
      int ty = r >> 2, hd2 = r & 3;
      float s = 0.f;
      #pragma unroll
      for (int k=0;k<16;k++)
        s += ld(eemb, ll*48 + ty*16 + k) * ld(a_edge, ll*64 + hd2*16 + k);
      ebt[t] = s * LOG2E;     // ebt[ll*16 + ty*4 + hd]
    }
  }
  {
    #pragma unroll
    for (int idx = t; idx < 1024; idx += 256){
      int row = idx >> 4, chunk = idx & 15;
      float4 wv = *((const float4*)((const float*)W + row*64 + chunk*4));
      *((float4*)&wlT[row*68 + chunk*4]) = wv;
    }
  }
  {
    long nfbase = ((long)b0*NN + (long)lb*32)*22;
    for (int idx = t; idx < 704; idx += 256){
      int row = idx / 22, k = idx - row*22;
      nfl[row*24 + k] = ld(nf, nfbase + idx);
    }
  }

  int w = t >> 6;
  int c = t & 63;
  int hd = c >> 4, dd = c & 15;
  long n0 = (long)lb*32 + w*8;

  float wreg[22];
  #pragma unroll
  for (int k = 0; k < 22; k++) wreg[k] = ld(pw, c*22 + k);
  float bias = ld(pb, c);
  __syncthreads();
  if (n0 >= nb*NN) return;

  #pragma unroll
  for (int i=0;i<8;i++){
    const float* nr = nfl + (w*8+i)*24;
    float a = bias;
    #pragma unroll
    for (int kc = 0; kc < 5; kc++){
      float4 nv = *((const float4*)&nr[kc*4]);
      a += nv.x*wreg[kc*4] + nv.y*wreg[kc*4+1] + nv.z*wreg[kc*4+2] + nv.w*wreg[kc*4+3];
    }
    a += nr[20]*wreg[20] + nr[21]*wreg[21];
    xs[(w*8+i)*68 + c] = a;
  }

  float acc[8] = {0.f,0.f,0.f,0.f,0.f,0.f,0.f,0.f};
  const float* xw = xs + (w*8)*68;
  const float* wr2 = wlT + c*68;
  #pragma unroll 4
  for (int kk=0;kk<16;kk++){
    float4 wv = *((const float4*)&wr2[kk*4]);
    #pragma unroll
    for (int i=0;i<8;i++){
      float4 xv = *((const float4*)&xw[i*68 + kk*4]);
      acc[i] += xv.x*wv.x + xv.y*wv.y + xv.z*wv.z + xv.w*wv.w;
    }
  }

  float cas = ld(a_src, c) * LOG2E;
  float cad = ld(a_dst, c) * LOG2E;
  #pragma unroll
  for (int i=0;i<8;i++){
    h[(n0+i)*64 + c] = acc[i];
    float ps = acc[i]*cas, pd = acc[i]*cad;
    #pragma unroll
    for (int o=8;o>=1;o>>=1){
      ps += __shfl_xor(ps,o,64);
      pd += __shfl_xor(pd,o,64);
    }
    if (dd == 0){
      sdot[(n0+i)*8 + hd]     = ps;
      sdot[(n0+i)*8 + 4 + hd] = pd;
    }
  }
}

// SIMD-transposed GAT aggregation for one node (wave-cooperative)
__device__ __forceinline__ float gat_node(const float* __restrict__ hb,
    const float* __restrict__ sb, const unsigned short* __restrict__ cb, int dg,
    float sdP, float ebP0, float ebP1, float ebP2,
    float hdst, int c, int hd,
    const void* lng, const void* lnb, int l){
  int hL = c & 3;
  float denP = 0.f, acc = 0.f;
  int npass = (dg + 15) >> 4;
  for (int p = 0; p < npass; p++){
    int eidx = (p << 4) + (c >> 2);
    int pk = cb[eidx];
    int src = pk & 4095, ty = (pk >> 12) & 3;
    float av = sb[src*8 + hL] + sdP + (ty==0?ebP0:(ty==1?ebP1:ebP2));
    av = fmaxf(av, 0.2f*av);
    float ev = exp2f(av);
    if (eidx >= dg) ev = 0.f;
    denP += ev;
    int jmax = dg - (p << 4); if (jmax > 16) jmax = 16;
    #pragma unroll 4
    for (int j = 0; j < jmax; j++){
      float evj = __shfl(ev, j*4 + hd, 64);
      int sj = __builtin_amdgcn_readlane(pk, j*4) & 4095;
      acc += hb[(long)sj*64 + c] * evj;
    }
  }
  #pragma unroll
  for (int o=4;o<=32;o<<=1) denP += __shfl_xor(denP, o, 64);
  float den = __shfl(denP, hd, 64);
  float y = acc / (den + 1e-10f) + hdst;

  float s = y;
  #pragma unroll
  for (int o=32;o>=1;o>>=1) s += __shfl_xor(s, o, 64);
  float mean = s * (1.f/64.f);
  float d = y - mean;
  float vs = d*d;
  #pragma unroll
  for (int o=32;o>=1;o>>=1) vs += __shfl_xor(vs, o, 64);
  float var = vs * (1.f/64.f);
  float outv = d * rsqrtf(var + 1e-5f) * ld(lng, l*64+c) + ld(lnb, l*64+c);
  return gelu_f(outv);
}

// shared tail of the GAT+linear fusion: write h/sdot for layer l+1 (global)
__device__ __forceinline__ void gat_linear_tail(float g, float* xs, const float* wlT,
    const void* a_src, const void* a_dst, float* __restrict__ hOut,
    float* __restrict__ sdOut, long wave, int wloc, int c, int hd, int dd, int l){
  xs[wloc*68 + c] = g;
  float ha = 0.f;
  const float* xw = xs + wloc*68;
  const float* wr = wlT + c*68;
  #pragma unroll 4
  for (int kk=0;kk<16;kk++){
    float4 xv = *((const float4*)&xw[kk*4]);
    float4 wv = *((const float4*)&wr[kk*4]);
    ha += xv.x*wv.x + xv.y*wv.y + xv.z*wv.z + xv.w*wv.w;
  }
  hOut[wave*64 + c] = ha;
  float cas = ld(a_src, (long)(l+1)*64 + c) * LOG2E;
  float cad = ld(a_dst, (long)(l+1)*64 + c) * LOG2E;
  float ps = ha*cas, pd = ha*cad;
  #pragma unroll
  for (int o=8;o>=1;o>>=1){
    ps += __shfl_xor(ps,o,64);
    pd += __shfl_xor(pd,o,64);
  }
  if (dd == 0){
    sdOut[wave*8 + hd]     = ps;
    sdOut[wave*8 + 4 + hd] = pd;
  }
}

// GAT(0)+linear(1), PRUNED to the 2-HOP cone of the center node.
__global__ __launch_bounds__(256) void k_gatcone(
    const float* __restrict__ hIn, const float* __restrict__ sdIn,
    const float* __restrict__ ebt,
    const int* __restrict__ cursor, const unsigned short* __restrict__ csr,
    const void* __restrict__ lng, const void* __restrict__ lnb,
    const void* __restrict__ W,
    const void* __restrict__ a_src, const void* __restrict__ a_dst,
    float* __restrict__ hOut, float* __restrict__ sdOut,
    int l, int nb){
  __attribute__((aligned(16))) __shared__ float wlT[64*68];
  __attribute__((aligned(16))) __shared__ float xs[4*68];
  int t = threadIdx.x;
  int wloc = t >> 6;
  int b  = (int)blockIdx.x % nb;
  int ib = (int)blockIdx.x / nb;
  long wcen = (long)b*NN + NN/2;
  int dgc = cursor[wcen];
  dgc = (dgc < 0) ? 0 : (dgc > 64 ? 64 : dgc);
  int e0 = ib*4;
  if (e0/65 > dgc) return;           // block-uniform: all 4 waves out of range
  {
    #pragma unroll
    for (int idx = t; idx < 1024; idx += 256){
      int row = idx >> 4, chunk = idx & 15;
      float4 wv = *((const float4*)((const float*)W + (long)(l+1)*4096 + row*64 + chunk*4));
      *((float4*)&wlT[row*68 + chunk*4]) = wv;
    }
  }
  __syncthreads();

  int e = e0 + wloc;
  int i = e / 65, j = e - i*65;
  long wave = -1;
  if (e < 4225 && i <= dgc){
    long vi = (i == 0) ? wcen : (long)b*NN + (csr[wcen*64 + (i-1)] & 4095);
    int dgi = cursor[vi];
    dgi = (dgi < 0) ? 0 : (dgi > 64 ? 64 : dgi);
    if (j == 0)            wave = vi;
    else if (j <= dgi)     wave = (long)b*NN + (csr[vi*64 + (j-1)] & 4095);
  }
  if (wave < 0) return;              // wave-uniform exit

  int c  = t & 63;
  int hd = c >> 4, dd = c & 15, hL = c & 3;

  float ebP0 = ebt[l*16 + 0 + hL];
  float ebP1 = ebt[l*16 + 4 + hL];
  float ebP2 = ebt[l*16 + 8 + hL];
  float sdP  = sdIn[wave*8 + 4 + hL];
  float hdst = hIn[wave*64 + c];
  int dg = __builtin_amdgcn_readfirstlane(cursor[wave]);
  dg = (dg < 0) ? 0 : (dg > 64 ? 64 : dg);
  const unsigned short* cb = csr + wave*64;
  const float* hb = hIn + (long)b*NN*64;
  const float* sb = sdIn + (long)b*NN*8;

  float g = gat_node(hb, sb, cb, dg, sdP, ebP0, ebP1, ebP2, hdst, c, hd, lng, lnb, l);
  gat_linear_tail(g, xs, wlT, a_src, a_dst, hOut, sdOut, wave, wloc, c, hd, dd, l);
}

// Layers 2+3 merged: one 1024-thread block per batch.
// Phase 1 (16 waves, 5 rounds): GAT(1)+linear(2) for S1 = {center} u csr[center],
// results kept in LDS (h2L/sd2L). Phase 2 (wave 0): GAT(2) for the center reading
// LDS by S1 slot index (slot j of csr[center] == LDS entry j+1) -> cemb.
__global__ __launch_bounds__(1024) void k_gat23(
    const float* __restrict__ hIn, const float* __restrict__ sdIn,   // layer-1 h/sdot (hB/sdotB)
    const float* __restrict__ ebt,
    const int* __restrict__ cursor, const unsigned short* __restrict__ csr,
    const void* __restrict__ lng, const void* __restrict__ lnb,
    const void* __restrict__ W,
    const void* __restrict__ a_src, const void* __restrict__ a_dst,
    float* __restrict__ cemb, int b0, int nb){
  __attribute__((aligned(16))) __shared__ float wlT[64*68];   // W[2] row-per-lane
  __attribute__((aligned(16))) __shared__ float xsL[16*68];
  __attribute__((aligned(16))) __shared__ float h2L[65*68];   // layer-2 h for S1 entries
  __shared__ float sd2L[65*9];                                // layer-2 sdot for S1 entries
  int t = threadIdx.x;
  int b = (int)blockIdx.x;
  if (b >= nb) return;
  { // stage W[2]: 1024 float4s, one per thread
    int row = t >> 4, chunk = t & 15;
    float4 wv = *((const float4*)((const float*)W + 2*4096 + row*64 + chunk*4));
    *((float4*)&wlT[row*68 + chunk*4]) = wv;
  }
  long wcen = (long)b*NN + NN/2;
  int dgc = cursor[wcen];
  dgc = (dgc < 0) ? 0 : (dgc > 64 ? 64 : dgc);
  int wv = t >> 6, c = t & 63;
  int hd = c >> 4, dd = c & 15, hL = c & 3;
  const float* hb = hIn + (long)b*NN*64;
  const float* sb = sdIn + (long)b*NN*8;
  float eb10 = ebt[16 + 0 + hL], eb11 = ebt[16 + 4 + hL], eb12 = ebt[16 + 8 + hL];
  float cas2 = ld(a_src, 2*64 + c) * LOG2E;
  float cad2 = ld(a_dst, 2*64 + c) * LOG2E;
  __syncthreads();

  // ---- phase 1: S1 nodes, layer-1 GAT + linear(2) -> LDS ----
  for (int r = 0; r < 5; r++){
    int e = r*16 + wv;                     // wave-uniform entry id
    if (e < 65 && e <= dgc){
      long wave = (e == 0) ? wcen : (long)b*NN + (csr[wcen*64 + (e-1)] & 4095);
      float sdP  = sdIn[wave*8 + 4 + hL];
      float hdst = hIn[wave*64 + c];
      int dg = __builtin_amdgcn_readfirstlane(cursor[wave]);
      dg = (dg < 0) ? 0 : (dg > 64 ? 64 : dg);
      const unsigned short* cb = csr + wave*64;
      float g = gat_node(hb, sb, cb, dg, sdP, eb10, eb11, eb12, hdst, c, hd, lng, lnb, 1);
      xsL[wv*68 + c] = g;
      float ha = 0.f;
      const float* xw = xsL + wv*68;
      const float* wr = wlT + c*68;
      #pragma unroll 4
      for (int kk=0;kk<16;kk++){
        float4 xv = *((const float4*)&xw[kk*4]);
        float4 wvv = *((const float4*)&wr[kk*4]);
        ha += xv.x*wvv.x + xv.y*wvv.y + xv.z*wvv.z + xv.w*wvv.w;
      }
      h2L[e*68 + c] = ha;
      float ps = ha*cas2, pd = ha*cad2;
      #pragma unroll
      for (int o=8;o>=1;o>>=1){
        ps += __shfl_xor(ps,o,64);
        pd += __shfl_xor(pd,o,64);
      }
      if (dd == 0){
        sd2L[e*9 + hd]     = ps;
        sd2L[e*9 + 4 + hd] = pd;
      }
    }
  }
  __syncthreads();

  // ---- phase 2: center node, layer-2 GAT, all inputs in LDS ----
  if (t < 64){
    float eb0 = ebt[32 + 0 + hL], eb1 = ebt[32 + 4 + hL], eb2 = ebt[32 + 8 + hL];
    float sdP  = sd2L[4 + hL];             // center's dst-dot (entry 0)
    float hdst = h2L[c];                   // center's h2 (entry 0)
    int dg = dgc;
    const unsigned short* cb = csr + wcen*64;
    float denP = 0.f, acc = 0.f;
    int npass = (dg + 15) >> 4;
    for (int p = 0; p < npass; p++){
      int eidx = (p << 4) + (c >> 2);      // slot in csr[center], <= 63
      int pk = cb[eidx];
      int ty = (pk >> 12) & 3;
      float av = sd2L[(eidx+1)*9 + hL] + sdP + (ty==0?eb0:(ty==1?eb1:eb2));
      av = fmaxf(av, 0.2f*av);
      float ev = exp2f(av);
      if (eidx >= dg) ev = 0.f;
      denP += ev;
      int jmax = dg - (p << 4); if (jmax > 16) jmax = 16;
      #pragma unroll 4
      for (int j = 0; j < jmax; j++){
        float evj = __shfl(ev, j*4 + hd, 64);
        acc += h2L[(p*16 + j + 1)*68 + c] * evj;   // slot -> LDS entry j+1
      }
    }
    #pragma unroll
    for (int o=4;o<=32;o<<=1) denP += __shfl_xor(denP, o, 64);
    float den = __shfl(denP, hd, 64);
    float y = acc / (den + 1e-10f) + hdst;
    float s = y;
    #pragma unroll
    for (int o=32;o>=1;o>>=1) s += __shfl_xor(s, o, 64);
    float mean = s * (1.f/64.f);
    float d = y - mean;
    float vs = d*d;
    #pragma unroll
    for (int o=32;o>=1;o>>=1) vs += __shfl_xor(vs, o, 64);
    float var = vs * (1.f/64.f);
    float outv = d * rsqrtf(var + 1e-5f) * ld(lng, 2*64+c) + ld(lnb, 2*64+c);
    cemb[(b0+b)*64 + c] = gelu_f(outv);
  }
}

// enc1 with in-block fused construction (reads center embedding from cemb)
__global__ __launch_bounds__(256) void k_enc1(const float* __restrict__ ctr,
    const void* rnafm, const void* edelta, const void* hand,
    const void* gow, const void* gob,
    const void* e1w, const void* e1b, float* __restrict__ g1){
  __shared__ float fb[1384];
  __shared__ float femb[64];
  int b = blockIdx.x, t = threadIdx.x;
  for (int i=t;i<640;i+=256){
    fb[i]     = ld(rnafm,  b*640+i);
    fb[704+i] = ld(edelta, b*640+i);
  }
  if (t<40) fb[1344+t] = ld(hand, b*40+t);
  if (t>=64 && t<128){
    int cc = t-64;
    femb[cc] = ctr[b*64+cc];
  }
  __syncthreads();
  if (t<64){
    float acc = ld(gob, t);
    #pragma unroll 8
    for (int k=0;k<64;k++) acc += femb[k]*ld(gow, t*64+k);
    fb[640+t] = acc;
  }
  __syncthreads();
  int w = t >> 6, lane = t & 63;
  int c = blockIdx.y*4 + w;
  long wr = (long)c*1384;
  float acc = 0.f;
  #pragma unroll 7
  for (int i=0;i<21;i++){
    int k = lane + 64*i;
    acc += fb[k]*ld(e1w, wr+k);
  }
  if (lane < 40){
    int k = 1344+lane;
    acc += fb[k]*ld(e1w, wr+k);
  }
  #pragma unroll
  for (int o=32;o>=1;o>>=1) acc += __shfl_xor(acc, o, 64);
  if (lane==0) g1[b*256+c] = gelu_f(acc + ld(e1b, c));
}

// enc2 with integrated LayerNorm
__global__ __launch_bounds__(256) void k_enc2(const float* __restrict__ g1,
    const void* lng, const void* lnb, const void* e2w, const void* e2b,
    float* __restrict__ shs, float* __restrict__ out){
  __shared__ float red[256];
  __shared__ float h1s[256];
  int b = blockIdx.x, t = threadIdx.x;
  float g = g1[b*256+t];
  red[t] = g; __syncthreads();
  for (int s=128;s>=1;s>>=1){ if (t<s) red[t]+=red[t+s]; __syncthreads(); }
  float mean = red[0]*(1.f/256.f); __syncthreads();
  red[t] = (g-mean)*(g-mean); __syncthreads();
  for (int s=128;s>=1;s>>=1){ if (t<s) red[t]+=red[t+s]; __syncthreads(); }
  float var = red[0]*(1.f/256.f);
  h1s[t] = (g-mean)*rsqrtf(var+1e-5f)*ld(lng, t) + ld(lnb, t);
  __syncthreads();
  int w = t >> 6, lane = t & 63;
  int c = blockIdx.y*4 + w;
  long wr = (long)c*256;
  float acc = 0.f;
  #pragma unroll
  for (int i=0;i<4;i++){
    int k = lane + 64*i;
    acc += h1s[k]*ld(e2w, wr+k);
  }
  #pragma unroll
  for (int o=32;o>=1;o>>=1) acc += __shfl_xor(acc, o, 64);
  if (lane==0){
    float s = gelu_f(acc + ld(e2b, c));
    shs[b*128+c] = s;
    out[96 + b*128 + c] = s;
  }
}

// mid (adapter/cls hidden) + final heads via per-batch atomic ticket:
// all 56 blocks of batch b write a1s/c1s, release-fence + atomicAdd;
// the 56th block acquires and computes the tiny heads.
__global__ __launch_bounds__(256) void k_midfin(const float* __restrict__ shs,
    const void* a1w, const void* a1b, const void* c1w, const void* c1b,
    const void* binw, const void* binb, const void* a2w, const void* a2b,
    const void* c2w, const void* c2b,
    float* __restrict__ a1s, float* __restrict__ c1s,
    int* __restrict__ ticket, float* __restrict__ out){
  int b = blockIdx.x;
  int w = threadIdx.x >> 6, lane = threadIdx.x & 63;
  int idx = blockIdx.y*4 + w;
  const float* sb = shs + b*128;
  if (idx < 160){
    long wr = (long)idx*128;
    float acc = sb[lane]*ld(a1w, wr+lane) + sb[lane+64]*ld(a1w, wr+lane+64);
    #pragma unroll
    for (int o=32;o>=1;o>>=1) acc += __shfl_xor(acc, o, 64);
    if (lane==0) a1s[b*160+idx] = gelu_f(acc + ld(a1b, idx));
  } else {
    int c = idx - 160;
    long wr = (long)c*128;
    float acc = sb[lane]*ld(c1w, wr+lane) + sb[lane+64]*ld(c1w, wr+lane+64);
    #pragma unroll
    for (int o=32;o>=1;o>>=1) acc += __shfl_xor(acc, o, 64);
    if (lane==0) c1s[b*64+c] = gelu_f(acc + ld(c1b, c));
  }
  __threadfence();                      // release a1s/c1s
  __shared__ int lastf;
  if (threadIdx.x == 0) lastf = (atomicAdd(&ticket[b], 1) == 55);
  __syncthreads();
  if (!lastf) return;
  __threadfence();                      // acquire
  int t = threadIdx.x;
  if (t < 64){
    {
      float p = sb[t]*ld(binw, t) + sb[t+64]*ld(binw, t+64);
      #pragma unroll
      for (int o=32;o>=1;o>>=1) p += __shfl_xor(p, o, 64);
      if (t==0) out[b] = p + ld(binb, 0);
    }
    if (t<5){
      float acc = ld(a2b, t);
      for (int i=0;i<32;i++) acc += a1s[b*160 + t*32+i]*ld(a2w, t*32+i);
      out[8 + b*5 + t] = acc;
    }
    if (t>=8 && t<14){
      int o = t-8;
      float acc = ld(c2b, o);
      for (int j=0;j<64;j++) acc += c1s[b*64+j]*ld(c2w, o*64+j);
      out[48 + b*6 + o] = acc;
    }
  }
}

extern "C" void kernel_launch(void* const* d_in, const int* in_sizes, int n_in,
                              void* d_out, int out_size, void* d_ws, size_t ws_size,
                              hipStream_t stream) {
  const int* ei  = (const int*)d_in[4];
  const int* ety = (const int*)d_in[5];

  size_t need_full = 2048 + 512
                   + (size_t)4*((size_t)BB*NN)
                   + (size_t)4*((size_t)BB*NN*64)
                   + (size_t)4*3*((size_t)BB*NN*64)
                   + (size_t)4*2*((size_t)BB*NN*8)
                   + (size_t)4*(8*256 + 8*128 + 8*160 + 8*64 + 64);
  int nb = (ws_size >= need_full + (1u<<20)) ? BB : 1;

  char* ws = (char*)d_ws;
  float* cemb    = (float*)ws;
  float* ebt     = (float*)(ws + 2048 + 256);
  int*   cursor  = (int*)(ws + 2048 + 512);
  int*   ticket  = cursor + (size_t)nb*NN;                       // 64 ints
  unsigned short* csr = (unsigned short*)(ticket + 64);          // nb*NN*64 ushorts
  float* hA      = (float*)((char*)csr + (size_t)nb*NN*64*2);
  float* hB      = hA + (size_t)nb*NN*64;
  float* sdotA   = hB + (size_t)nb*NN*64;
  float* sdotB   = sdotA + (size_t)nb*NN*8;
  float* g1      = sdotB + (size_t)nb*NN*8;
  float* shs     = g1 + 8*256;
  float* a1s     = shs + 8*128;
  float* c1s     = a1s + 8*160;

  for (int b0 = 0; b0 < BB; b0 += nb){
    hipMemsetAsync(cursor, 0, ((size_t)nb*NN + 64)*sizeof(int), stream);
    int NL = nb*NN/32;
    int NF = nb*(EE/1024);
    hipLaunchKernelGGL(k_pre, dim3(NF+NL), dim3(256), 0, stream,
                       d_in[3], d_in[6], d_in[7],
                       d_in[8], d_in[9], d_in[10], d_in[11], d_in[12],
                       ei, ety, hA, sdotA, ebt, cursor, csr, b0, nb, NF);
    hipLaunchKernelGGL(k_gatcone, dim3(nb*1057), dim3(256), 0, stream,
                       hA, sdotA, ebt, cursor, csr, d_in[13], d_in[14],
                       d_in[8], d_in[9], d_in[10], hB, sdotB, 0, nb);
    hipLaunchKernelGGL(k_gat23, dim3(nb), dim3(1024), 0, stream,
                       hB, sdotB, ebt, cursor, csr, d_in[13], d_in[14],
                       d_in[8], d_in[9], d_in[10], cemb, b0, nb);
  }

  hipLaunchKernelGGL(k_enc1, dim3(BB, 64), dim3(256), 0, stream,
                     cemb,
                     d_in[0], d_in[1], d_in[2], d_in[15], d_in[16],
                     d_in[17], d_in[18], g1);
  hipLaunchKernelGGL(k_enc2, dim3(BB, 32), dim3(256), 0, stream,
                     g1, d_in[19], d_in[20], d_in[21], d_in[22], shs, (float*)d_out);
  hipLaunchKernelGGL(k_midfin, dim3(BB, 56), dim3(256), 0, stream,
                     shs, d_in[25], d_in[26], d_in[29], d_in[30],
                     d_in[23], d_in[24], d_in[27], d_in[28], d_in[31], d_in[32],
                     a1s, c1s, ticket, (float*)d_out);
}

// Round 9
// 213.982 us; speedup vs baseline: 1.1635x; 1.1635x over previous
//
#include <hip/hip_runtime.h>
#include <hip/hip_bf16.h>
#include <math.h>

#define BB 8
#define NN 4096
#define EE 65536
#define LOG2E 1.4426950408889634f

__device__ __forceinline__ float my_erf(float x){
  float ax = fabsf(x);
  float tt = 1.f/(1.f + 0.3275911f*ax);
  float poly = ((((1.061405429f*tt - 1.453152027f)*tt + 1.421413741f)*tt
                 - 0.284496736f)*tt + 0.254829592f)*tt;
  float y = 1.f - poly*expf(-ax*ax);
  return x >= 0.f ? y : -y;
}
__device__ __forceinline__ float gelu_f(float x){ return 0.5f*x*(1.0f + my_erf(x*0.7071067811865476f)); }
__device__ __forceinline__ float ld(const void* p, long i){ return ((const float*)p)[i]; }

// merged: CSR fill (blocks [0,NF), XCD-batch-bound) + layer-0 projection+linear (blocks [NF,NF+NL))
// CSR entries are USHORT: src(12b) | type(2b)<<12 — halves scatter footprint.
__global__ __launch_bounds__(256) void k_pre(
    const void* __restrict__ nf, const void* __restrict__ pw, const void* __restrict__ pb,
    const void* __restrict__ W, const void* __restrict__ a_src, const void* __restrict__ a_dst,
    const void* __restrict__ a_edge, const void* __restrict__ eemb,
    const int* __restrict__ ei, const int* __restrict__ ety,
    float* __restrict__ h, float* __restrict__ sdot, float* __restrict__ ebt,
    int* __restrict__ cursor, unsigned short* __restrict__ csr, int b0, int nb, int NF){
  if ((int)blockIdx.x < NF){
    // ---- CSR fill: 4 edges/thread via int4; one batch per XCD ----
    int fi = (int)blockIdx.x;
    int bpb = NF / nb;
    int b, q;
    if (nb == BB){ b = fi & 7; q = fi >> 3; }
    else         { b = fi / bpb; q = fi - b*bpb; }
    int e4 = q*256 + threadIdx.x;
    const int* base = ei + (long)(b0+b)*2*EE;
    int4 s4 = ((const int4*)base)[e4];
    int4 d4 = ((const int4*)(base + EE))[e4];
    int4 t4 = ((const int4*)(ety + (long)(b0+b)*EE))[e4];
    int* cb = cursor + b*NN;
    int ss[4] = {s4.x & (NN-1), s4.y & (NN-1), s4.z & (NN-1), s4.w & (NN-1)};
    int dd[4] = {d4.x & (NN-1), d4.y & (NN-1), d4.z & (NN-1), d4.w & (NN-1)};
    int tt[4] = {t4.x, t4.y, t4.z, t4.w};
    #pragma unroll
    for (int i=0;i<4;i++){
      int ty = tt[i]; ty = (ty < 0) ? 0 : (ty > 2 ? 2 : ty);
      int p = atomicAdd(&cb[dd[i]], 1);
      if (p < 64) csr[((long)(b*NN) + dd[i])*64 + p] = (unsigned short)(ss[i] | (ty << 12));
    }
    return;
  }

  // ---- projection 22->64 + linear0 64x64 + sdot ----
  __attribute__((aligned(16))) __shared__ float wlT[64*68];
  __attribute__((aligned(16))) __shared__ float nfl[32*24];
  __attribute__((aligned(16))) __shared__ float xs[32*68];
  int t = threadIdx.x;
  int lb = (int)blockIdx.x - NF;

  if (lb == 0 && t < 48){
    int ll = t >> 4, r = t & 15;
    if (r < 12){
      int ty = r >> 2, hd2 = r & 3;
      float s = 0.f;
      #pragma unroll
      for (int k=0;k<16;k++)
        s += ld(eemb, ll*48 + ty*16 + k) * ld(a_edge, ll*64 + hd2*16 + k);
      ebt[t] = s * LOG2E;     // ebt[ll*16 + ty*4 + hd]
    }
  }
  {
    #pragma unroll
    for (int idx = t; idx < 1024; idx += 256){
      int row = idx >> 4, chunk = idx & 15;
      float4 wv = *((const float4*)((const float*)W + row*64 + chunk*4));
      *((float4*)&wlT[row*68 + chunk*4]) = wv;
    }
  }
  {
    long nfbase = ((long)b0*NN + (long)lb*32)*22;
    for (int idx = t; idx < 704; idx += 256){
      int row = idx / 22, k = idx - row*22;
      nfl[row*24 + k] = ld(nf, nfbase + idx);
    }
  }

  int w = t >> 6;
  int c = t & 63;
  int hd = c >> 4, dd = c & 15;
  long n0 = (long)lb*32 + w*8;

  float wreg[22];
  #pragma unroll
  for (int k = 0; k < 22; k++) wreg[k] = ld(pw, c*22 + k);
  float bias = ld(pb, c);
  __syncthreads();
  if (n0 >= nb*NN) return;

  #pragma unroll
  for (int i=0;i<8;i++){
    const float* nr = nfl + (w*8+i)*24;
    float a = bias;
    #pragma unroll
    for (int kc = 0; kc < 5; kc++){
      float4 nv = *((const float4*)&nr[kc*4]);
      a += nv.x*wreg[kc*4] + nv.y*wreg[kc*4+1] + nv.z*wreg[kc*4+2] + nv.w*wreg[kc*4+3];
    }
    a += nr[20]*wreg[20] + nr[21]*wreg[21];
    xs[(w*8+i)*68 + c] = a;
  }

  float acc[8] = {0.f,0.f,0.f,0.f,0.f,0.f,0.f,0.f};
  const float* xw = xs + (w*8)*68;
  const float* wr2 = wlT + c*68;
  #pragma unroll 4
  for (int kk=0;kk<16;kk++){
    float4 wv = *((const float4*)&wr2[kk*4]);
    #pragma unroll
    for (int i=0;i<8;i++){
      float4 xv = *((const float4*)&xw[i*68 + kk*4]);
      acc[i] += xv.x*wv.x + xv.y*wv.y + xv.z*wv.z + xv.w*wv.w;
    }
  }

  float cas = ld(a_src, c) * LOG2E;
  float cad = ld(a_dst, c) * LOG2E;
  #pragma unroll
  for (int i=0;i<8;i++){
    h[(n0+i)*64 + c] = acc[i];
    float ps = acc[i]*cas, pd = acc[i]*cad;
    #pragma unroll
    for (int o=8;o>=1;o>>=1){
      ps += __shfl_xor(ps,o,64);
      pd += __shfl_xor(pd,o,64);
    }
    if (dd == 0){
      sdot[(n0+i)*8 + hd]     = ps;
      sdot[(n0+i)*8 + 4 + hd] = pd;
    }
  }
}

// SIMD-transposed GAT aggregation for one node (wave-cooperative)
__device__ __forceinline__ float gat_node(const float* __restrict__ hb,
    const float* __restrict__ sb, const unsigned short* __restrict__ cb, int dg,
    float sdP, float ebP0, float ebP1, float ebP2,
    float hdst, int c, int hd,
    const void* lng, const void* lnb, int l){
  int hL = c & 3;
  float denP = 0.f, acc = 0.f;
  int npass = (dg + 15) >> 4;
  for (int p = 0; p < npass; p++){
    int eidx = (p << 4) + (c >> 2);
    int pk = cb[eidx];
    int src = pk & 4095, ty = (pk >> 12) & 3;
    float av = sb[src*8 + hL] + sdP + (ty==0?ebP0:(ty==1?ebP1:ebP2));
    av = fmaxf(av, 0.2f*av);
    float ev = exp2f(av);
    if (eidx >= dg) ev = 0.f;
    denP += ev;
    int jmax = dg - (p << 4); if (jmax > 16) jmax = 16;
    #pragma unroll 4
    for (int j = 0; j < jmax; j++){
      float evj = __shfl(ev, j*4 + hd, 64);
      int sj = __builtin_amdgcn_readlane(pk, j*4) & 4095;
      acc += hb[(long)sj*64 + c] * evj;
    }
  }
  #pragma unroll
  for (int o=4;o<=32;o<<=1) denP += __shfl_xor(denP, o, 64);
  float den = __shfl(denP, hd, 64);
  float y = acc / (den + 1e-10f) + hdst;

  float s = y;
  #pragma unroll
  for (int o=32;o>=1;o>>=1) s += __shfl_xor(s, o, 64);
  float mean = s * (1.f/64.f);
  float d = y - mean;
  float vs = d*d;
  #pragma unroll
  for (int o=32;o>=1;o>>=1) vs += __shfl_xor(vs, o, 64);
  float var = vs * (1.f/64.f);
  float outv = d * rsqrtf(var + 1e-5f) * ld(lng, l*64+c) + ld(lnb, l*64+c);
  return gelu_f(outv);
}

// shared tail of the GAT+linear fusion: write h/sdot for layer l+1 (global)
__device__ __forceinline__ void gat_linear_tail(float g, float* xs, const float* wlT,
    const void* a_src, const void* a_dst, float* __restrict__ hOut,
    float* __restrict__ sdOut, long wave, int wloc, int c, int hd, int dd, int l){
  xs[wloc*68 + c] = g;
  float ha = 0.f;
  const float* xw = xs + wloc*68;
  const float* wr = wlT + c*68;
  #pragma unroll 4
  for (int kk=0;kk<16;kk++){
    float4 xv = *((const float4*)&xw[kk*4]);
    float4 wv = *((const float4*)&wr[kk*4]);
    ha += xv.x*wv.x + xv.y*wv.y + xv.z*wv.z + xv.w*wv.w;
  }
  hOut[wave*64 + c] = ha;
  float cas = ld(a_src, (long)(l+1)*64 + c) * LOG2E;
  float cad = ld(a_dst, (long)(l+1)*64 + c) * LOG2E;
  float ps = ha*cas, pd = ha*cad;
  #pragma unroll
  for (int o=8;o>=1;o>>=1){
    ps += __shfl_xor(ps,o,64);
    pd += __shfl_xor(pd,o,64);
  }
  if (dd == 0){
    sdOut[wave*8 + hd]     = ps;
    sdOut[wave*8 + 4 + hd] = pd;
  }
}

// GAT(0)+linear(1), PRUNED to the 2-HOP cone of the center node.
__global__ __launch_bounds__(256) void k_gatcone(
    const float* __restrict__ hIn, const float* __restrict__ sdIn,
    const float* __restrict__ ebt,
    const int* __restrict__ cursor, const unsigned short* __restrict__ csr,
    const void* __restrict__ lng, const void* __restrict__ lnb,
    const void* __restrict__ W,
    const void* __restrict__ a_src, const void* __restrict__ a_dst,
    float* __restrict__ hOut, float* __restrict__ sdOut,
    int l, int nb){
  __attribute__((aligned(16))) __shared__ float wlT[64*68];
  __attribute__((aligned(16))) __shared__ float xs[4*68];
  int t = threadIdx.x;
  int wloc = t >> 6;
  int b  = (int)blockIdx.x % nb;
  int ib = (int)blockIdx.x / nb;
  long wcen = (long)b*NN + NN/2;
  int dgc = cursor[wcen];
  dgc = (dgc < 0) ? 0 : (dgc > 64 ? 64 : dgc);
  int e0 = ib*4;
  if (e0/65 > dgc) return;           // block-uniform: all 4 waves out of range
  {
    #pragma unroll
    for (int idx = t; idx < 1024; idx += 256){
      int row = idx >> 4, chunk = idx & 15;
      float4 wv = *((const float4*)((const float*)W + (long)(l+1)*4096 + row*64 + chunk*4));
      *((float4*)&wlT[row*68 + chunk*4]) = wv;
    }
  }
  __syncthreads();

  int e = e0 + wloc;
  int i = e / 65, j = e - i*65;
  long wave = -1;
  if (e < 4225 && i <= dgc){
    long vi = (i == 0) ? wcen : (long)b*NN + (csr[wcen*64 + (i-1)] & 4095);
    int dgi = cursor[vi];
    dgi = (dgi < 0) ? 0 : (dgi > 64 ? 64 : dgi);
    if (j == 0)            wave = vi;
    else if (j <= dgi)     wave = (long)b*NN + (csr[vi*64 + (j-1)] & 4095);
  }
  if (wave < 0) return;              // wave-uniform exit

  int c  = t & 63;
  int hd = c >> 4, dd = c & 15, hL = c & 3;

  float ebP0 = ebt[l*16 + 0 + hL];
  float ebP1 = ebt[l*16 + 4 + hL];
  float ebP2 = ebt[l*16 + 8 + hL];
  float sdP  = sdIn[wave*8 + 4 + hL];
  float hdst = hIn[wave*64 + c];
  int dg = __builtin_amdgcn_readfirstlane(cursor[wave]);
  dg = (dg < 0) ? 0 : (dg > 64 ? 64 : dg);
  const unsigned short* cb = csr + wave*64;
  const float* hb = hIn + (long)b*NN*64;
  const float* sb = sdIn + (long)b*NN*8;

  float g = gat_node(hb, sb, cb, dg, sdP, ebP0, ebP1, ebP2, hdst, c, hd, lng, lnb, l);
  gat_linear_tail(g, xs, wlT, a_src, a_dst, hOut, sdOut, wave, wloc, c, hd, dd, l);
}

// Layers 2+3 merged: one 1024-thread block per batch.
__global__ __launch_bounds__(1024) void k_gat23(
    const float* __restrict__ hIn, const float* __restrict__ sdIn,   // layer-1 h/sdot (hB/sdotB)
    const float* __restrict__ ebt,
    const int* __restrict__ cursor, const unsigned short* __restrict__ csr,
    const void* __restrict__ lng, const void* __restrict__ lnb,
    const void* __restrict__ W,
    const void* __restrict__ a_src, const void* __restrict__ a_dst,
    float* __restrict__ cemb, int b0, int nb){
  __attribute__((aligned(16))) __shared__ float wlT[64*68];   // W[2] row-per-lane
  __attribute__((aligned(16))) __shared__ float xsL[16*68];
  __attribute__((aligned(16))) __shared__ float h2L[65*68];   // layer-2 h for S1 entries
  __shared__ float sd2L[65*9];                                // layer-2 sdot for S1 entries
  int t = threadIdx.x;
  int b = (int)blockIdx.x;
  if (b >= nb) return;
  { // stage W[2]: 1024 float4s, one per thread
    int row = t >> 4, chunk = t & 15;
    float4 wv = *((const float4*)((const float*)W + 2*4096 + row*64 + chunk*4));
    *((float4*)&wlT[row*68 + chunk*4]) = wv;
  }
  long wcen = (long)b*NN + NN/2;
  int dgc = cursor[wcen];
  dgc = (dgc < 0) ? 0 : (dgc > 64 ? 64 : dgc);
  int wv = t >> 6, c = t & 63;
  int hd = c >> 4, dd = c & 15, hL = c & 3;
  const float* hb = hIn + (long)b*NN*64;
  const float* sb = sdIn + (long)b*NN*8;
  float eb10 = ebt[16 + 0 + hL], eb11 = ebt[16 + 4 + hL], eb12 = ebt[16 + 8 + hL];
  float cas2 = ld(a_src, 2*64 + c) * LOG2E;
  float cad2 = ld(a_dst, 2*64 + c) * LOG2E;
  __syncthreads();

  // ---- phase 1: S1 nodes, layer-1 GAT + linear(2) -> LDS ----
  for (int r = 0; r < 5; r++){
    int e = r*16 + wv;                     // wave-uniform entry id
    if (e < 65 && e <= dgc){
      long wave = (e == 0) ? wcen : (long)b*NN + (csr[wcen*64 + (e-1)] & 4095);
      float sdP  = sdIn[wave*8 + 4 + hL];
      float hdst = hIn[wave*64 + c];
      int dg = __builtin_amdgcn_readfirstlane(cursor[wave]);
      dg = (dg < 0) ? 0 : (dg > 64 ? 64 : dg);
      const unsigned short* cb = csr + wave*64;
      float g = gat_node(hb, sb, cb, dg, sdP, eb10, eb11, eb12, hdst, c, hd, lng, lnb, 1);
      xsL[wv*68 + c] = g;
      float ha = 0.f;
      const float* xw = xsL + wv*68;
      const float* wr = wlT + c*68;
      #pragma unroll 4
      for (int kk=0;kk<16;kk++){
        float4 xv = *((const float4*)&xw[kk*4]);
        float4 wvv = *((const float4*)&wr[kk*4]);
        ha += xv.x*wvv.x + xv.y*wvv.y + xv.z*wvv.z + xv.w*wvv.w;
      }
      h2L[e*68 + c] = ha;
      float ps = ha*cas2, pd = ha*cad2;
      #pragma unroll
      for (int o=8;o>=1;o>>=1){
        ps += __shfl_xor(ps,o,64);
        pd += __shfl_xor(pd,o,64);
      }
      if (dd == 0){
        sd2L[e*9 + hd]     = ps;
        sd2L[e*9 + 4 + hd] = pd;
      }
    }
  }
  __syncthreads();

  // ---- phase 2: center node, layer-2 GAT, all inputs in LDS ----
  if (t < 64){
    float eb0 = ebt[32 + 0 + hL], eb1 = ebt[32 + 4 + hL], eb2 = ebt[32 + 8 + hL];
    float sdP  = sd2L[4 + hL];             // center's dst-dot (entry 0)
    float hdst = h2L[c];                   // center's h2 (entry 0)
    int dg = dgc;
    const unsigned short* cb = csr + wcen*64;
    float denP = 0.f, acc = 0.f;
    int npass = (dg + 15) >> 4;
    for (int p = 0; p < npass; p++){
      int eidx = (p << 4) + (c >> 2);      // slot in csr[center], <= 63
      int pk = cb[eidx];
      int ty = (pk >> 12) & 3;
      float av = sd2L[(eidx+1)*9 + hL] + sdP + (ty==0?eb0:(ty==1?eb1:eb2));
      av = fmaxf(av, 0.2f*av);
      float ev = exp2f(av);
      if (eidx >= dg) ev = 0.f;
      denP += ev;
      int jmax = dg - (p << 4); if (jmax > 16) jmax = 16;
      #pragma unroll 4
      for (int j = 0; j < jmax; j++){
        float evj = __shfl(ev, j*4 + hd, 64);
        acc += h2L[(p*16 + j + 1)*68 + c] * evj;   // slot -> LDS entry j+1
      }
    }
    #pragma unroll
    for (int o=4;o<=32;o<<=1) denP += __shfl_xor(denP, o, 64);
    float den = __shfl(denP, hd, 64);
    float y = acc / (den + 1e-10f) + hdst;
    float s = y;
    #pragma unroll
    for (int o=32;o>=1;o>>=1) s += __shfl_xor(s, o, 64);
    float mean = s * (1.f/64.f);
    float d = y - mean;
    float vs = d*d;
    #pragma unroll
    for (int o=32;o>=1;o>>=1) vs += __shfl_xor(vs, o, 64);
    float var = vs * (1.f/64.f);
    float outv = d * rsqrtf(var + 1e-5f) * ld(lng, 2*64+c) + ld(lnb, 2*64+c);
    cemb[(b0+b)*64 + c] = gelu_f(outv);
  }
}

// enc1 with in-block fused construction (reads center embedding from cemb)
__global__ __launch_bounds__(256) void k_enc1(const float* __restrict__ ctr,
    const void* rnafm, const void* edelta, const void* hand,
    const void* gow, const void* gob,
    const void* e1w, const void* e1b, float* __restrict__ g1){
  __shared__ float fb[1384];
  __shared__ float femb[64];
  int b = blockIdx.x, t = threadIdx.x;
  for (int i=t;i<640;i+=256){
    fb[i]     = ld(rnafm,  b*640+i);
    fb[704+i] = ld(edelta, b*640+i);
  }
  if (t<40) fb[1344+t] = ld(hand, b*40+t);
  if (t>=64 && t<128){
    int cc = t-64;
    femb[cc] = ctr[b*64+cc];
  }
  __syncthreads();
  if (t<64){
    float acc = ld(gob, t);
    #pragma unroll 8
    for (int k=0;k<64;k++) acc += femb[k]*ld(gow, t*64+k);
    fb[640+t] = acc;
  }
  __syncthreads();
  int w = t >> 6, lane = t & 63;
  int c = blockIdx.y*4 + w;
  long wr = (long)c*1384;
  float acc = 0.f;
  #pragma unroll 7
  for (int i=0;i<21;i++){
    int k = lane + 64*i;
    acc += fb[k]*ld(e1w, wr+k);
  }
  if (lane < 40){
    int k = 1344+lane;
    acc += fb[k]*ld(e1w, wr+k);
  }
  #pragma unroll
  for (int o=32;o>=1;o>>=1) acc += __shfl_xor(acc, o, 64);
  if (lane==0) g1[b*256+c] = gelu_f(acc + ld(e1b, c));
}

// enc2 with integrated LayerNorm
__global__ __launch_bounds__(256) void k_enc2(const float* __restrict__ g1,
    const void* lng, const void* lnb, const void* e2w, const void* e2b,
    float* __restrict__ shs, float* __restrict__ out){
  __shared__ float red[256];
  __shared__ float h1s[256];
  int b = blockIdx.x, t = threadIdx.x;
  float g = g1[b*256+t];
  red[t] = g; __syncthreads();
  for (int s=128;s>=1;s>>=1){ if (t<s) red[t]+=red[t+s]; __syncthreads(); }
  float mean = red[0]*(1.f/256.f); __syncthreads();
  red[t] = (g-mean)*(g-mean); __syncthreads();
  for (int s=128;s>=1;s>>=1){ if (t<s) red[t]+=red[t+s]; __syncthreads(); }
  float var = red[0]*(1.f/256.f);
  h1s[t] = (g-mean)*rsqrtf(var+1e-5f)*ld(lng, t) + ld(lnb, t);
  __syncthreads();
  int w = t >> 6, lane = t & 63;
  int c = blockIdx.y*4 + w;
  long wr = (long)c*256;
  float acc = 0.f;
  #pragma unroll
  for (int i=0;i<4;i++){
    int k = lane + 64*i;
    acc += h1s[k]*ld(e2w, wr+k);
  }
  #pragma unroll
  for (int o=32;o>=1;o>>=1) acc += __shfl_xor(acc, o, 64);
  if (lane==0){
    float s = gelu_f(acc + ld(e2b, c));
    shs[b*128+c] = s;
    out[96 + b*128 + c] = s;
  }
}

__global__ __launch_bounds__(256) void k_mid(const float* __restrict__ shs,
    const void* a1w, const void* a1b, const void* c1w, const void* c1b,
    float* __restrict__ a1s, float* __restrict__ c1s){
  int b = blockIdx.x;
  int w = threadIdx.x >> 6, lane = threadIdx.x & 63;
  int idx = blockIdx.y*4 + w;
  const float* sb = shs + b*128;
  if (idx < 160){
    long wr = (long)idx*128;
    float acc = sb[lane]*ld(a1w, wr+lane) + sb[lane+64]*ld(a1w, wr+lane+64);
    #pragma unroll
    for (int o=32;o>=1;o>>=1) acc += __shfl_xor(acc, o, 64);
    if (lane==0) a1s[b*160+idx] = gelu_f(acc + ld(a1b, idx));
  } else {
    int c = idx - 160;
    long wr = (long)c*128;
    float acc = sb[lane]*ld(c1w, wr+lane) + sb[lane+64]*ld(c1w, wr+lane+64);
    #pragma unroll
    for (int o=32;o>=1;o>>=1) acc += __shfl_xor(acc, o, 64);
    if (lane==0) c1s[b*64+c] = gelu_f(acc + ld(c1b, c));
  }
}

__global__ __launch_bounds__(64) void k_fin(const float* __restrict__ shs,
    const float* __restrict__ a1s, const float* __restrict__ c1s,
    const void* binw, const void* binb, const void* a2w, const void* a2b,
    const void* c2w, const void* c2b,
    float* __restrict__ out){
  int b = blockIdx.x, t = threadIdx.x;
  {
    float p = shs[b*128+t]*ld(binw, t) + shs[b*128+t+64]*ld(binw, t+64);
    #pragma unroll
    for (int o=32;o>=1;o>>=1) p += __shfl_xor(p, o, 64);
    if (t==0) out[b] = p + ld(binb, 0);
  }
  if (t<5){
    float acc = ld(a2b, t);
    for (int i=0;i<32;i++) acc += a1s[b*160 + t*32+i]*ld(a2w, t*32+i);
    out[8 + b*5 + t] = acc;
  }
  if (t>=8 && t<14){
    int o = t-8;
    float acc = ld(c2b, o);
    for (int j=0;j<64;j++) acc += c1s[b*64+j]*ld(c2w, o*64+j);
    out[48 + b*6 + o] = acc;
  }
}

extern "C" void kernel_launch(void* const* d_in, const int* in_sizes, int n_in,
                              void* d_out, int out_size, void* d_ws, size_t ws_size,
                              hipStream_t stream) {
  const int* ei  = (const int*)d_in[4];
  const int* ety = (const int*)d_in[5];

  size_t need_full = 2048 + 512
                   + (size_t)4*((size_t)BB*NN)
                   + (size_t)4*((size_t)BB*NN*64)
                   + (size_t)4*3*((size_t)BB*NN*64)
                   + (size_t)4*2*((size_t)BB*NN*8)
                   + (size_t)4*(8*256 + 8*128 + 8*160 + 8*64 + 64);
  int nb = (ws_size >= need_full + (1u<<20)) ? BB : 1;

  char* ws = (char*)d_ws;
  float* cemb    = (float*)ws;
  float* ebt     = (float*)(ws + 2048 + 256);
  int*   cursor  = (int*)(ws + 2048 + 512);
  int*   ticket  = cursor + (size_t)nb*NN;                       // 64 ints (unused, layout kept)
  unsigned short* csr = (unsigned short*)(ticket + 64);          // nb*NN*64 ushorts
  float* hA      = (float*)((char*)csr + (size_t)nb*NN*64*2);
  float* hB      = hA + (size_t)nb*NN*64;
  float* sdotA   = hB + (size_t)nb*NN*64;
  float* sdotB   = sdotA + (size_t)nb*NN*8;
  float* g1      = sdotB + (size_t)nb*NN*8;
  float* shs     = g1 + 8*256;
  float* a1s     = shs + 8*128;
  float* c1s     = a1s + 8*160;

  for (int b0 = 0; b0 < BB; b0 += nb){
    hipMemsetAsync(cursor, 0, ((size_t)nb*NN + 64)*sizeof(int), stream);
    int NL = nb*NN/32;
    int NF = nb*(EE/1024);
    hipLaunchKernelGGL(k_pre, dim3(NF+NL), dim3(256), 0, stream,
                       d_in[3], d_in[6], d_in[7],
                       d_in[8], d_in[9], d_in[10], d_in[11], d_in[12],
                       ei, ety, hA, sdotA, ebt, cursor, csr, b0, nb, NF);
    hipLaunchKernelGGL(k_gatcone, dim3(nb*1057), dim3(256), 0, stream,
                       hA, sdotA, ebt, cursor, csr, d_in[13], d_in[14],
                       d_in[8], d_in[9], d_in[10], hB, sdotB, 0, nb);
    hipLaunchKernelGGL(k_gat23, dim3(nb), dim3(1024), 0, stream,
                       hB, sdotB, ebt, cursor, csr, d_in[13], d_in[14],
                       d_in[8], d_in[9], d_in[10], cemb, b0, nb);
  }

  hipLaunchKernelGGL(k_enc1, dim3(BB, 64), dim3(256), 0, stream,
                     cemb,
                     d_in[0], d_in[1], d_in[2], d_in[15], d_in[16],
                     d_in[17], d_in[18], g1);
  hipLaunchKernelGGL(k_enc2, dim3(BB, 32), dim3(256), 0, stream,
                     g1, d_in[19], d_in[20], d_in[21], d_in[22], shs, (float*)d_out);
  hipLaunchKernelGGL(k_mid,  dim3(BB, 56), dim3(256), 0, stream,
                     shs, d_in[25], d_in[26], d_in[29], d_in[30], a1s, c1s);
  hipLaunchKernelGGL(k_fin,  dim3(BB), dim3(64), 0, stream,
                     shs, a1s, c1s, d_in[23], d_in[24], d_in[27], d_in[28],
                     d_in[31], d_in[32], (float*)d_out);
}

// Round 10
// 210.688 us; speedup vs baseline: 1.1817x; 1.0156x over previous
//
#include <hip/hip_runtime.h>
#include <hip/hip_bf16.h>
#include <math.h>

#define BB 8
#define NN 4096
#define EE 65536
#define LOG2E 1.4426950408889634f

__device__ __forceinline__ float my_erf(float x){
  float ax = fabsf(x);
  float tt = 1.f/(1.f + 0.3275911f*ax);
  float poly = ((((1.061405429f*tt - 1.453152027f)*tt + 1.421413741f)*tt
                 - 0.284496736f)*tt + 0.254829592f)*tt;
  float y = 1.f - poly*expf(-ax*ax);
  return x >= 0.f ? y : -y;
}
__device__ __forceinline__ float gelu_f(float x){ return 0.5f*x*(1.0f + my_erf(x*0.7071067811865476f)); }
__device__ __forceinline__ float ld(const void* p, long i){ return ((const float*)p)[i]; }

// CSR fill + layer-0 projection+linear.
// NF>0  (nb==1 fallback): blocks [0,NF) are dedicated fill blocks (old split mode).
// NF==0 (nb==8): INTEGRATED mode — all 1024 blocks do linear work for nodes
//   blockIdx*32.. and additionally (threads t<128) fill 512 edges of batch
//   blockIdx&7 (XCD-bound: consecutive blocks round-robin XCDs, so batch b's
//   cursor/csr stay on XCD b's L2). Edge loads issue before LDS staging; the
//   atomic latency hides under the block's own matmul + co-resident waves.
__global__ __launch_bounds__(256) void k_pre(
    const void* __restrict__ nf, const void* __restrict__ pw, const void* __restrict__ pb,
    const void* __restrict__ W, const void* __restrict__ a_src, const void* __restrict__ a_dst,
    const void* __restrict__ a_edge, const void* __restrict__ eemb,
    const int* __restrict__ ei, const int* __restrict__ ety,
    float* __restrict__ h, float* __restrict__ sdot, float* __restrict__ ebt,
    int* __restrict__ cursor, unsigned short* __restrict__ csr, int b0, int nb, int NF){
  int t = threadIdx.x;
  int bi = (int)blockIdx.x;
  if (NF > 0 && bi < NF){
    // ---- dedicated fill block (nb==1 path): 4 edges/thread via int4 ----
    int bpb = NF / nb;
    int b = bi / bpb, q = bi - b*bpb;
    int e4 = q*256 + t;
    const int* base = ei + (long)(b0+b)*2*EE;
    int4 s4 = ((const int4*)base)[e4];
    int4 d4 = ((const int4*)(base + EE))[e4];
    int4 t4 = ((const int4*)(ety + (long)(b0+b)*EE))[e4];
    int* cb = cursor + b*NN;
    int ss[4] = {s4.x & (NN-1), s4.y & (NN-1), s4.z & (NN-1), s4.w & (NN-1)};
    int dd[4] = {d4.x & (NN-1), d4.y & (NN-1), d4.z & (NN-1), d4.w & (NN-1)};
    int tt[4] = {t4.x, t4.y, t4.z, t4.w};
    #pragma unroll
    for (int i=0;i<4;i++){
      int ty = tt[i]; ty = (ty < 0) ? 0 : (ty > 2 ? 2 : ty);
      int p = atomicAdd(&cb[dd[i]], 1);
      if (p < 64) csr[((long)(b*NN) + dd[i])*64 + p] = (unsigned short)(ss[i] | (ty << 12));
    }
    return;
  }
  int lb = bi - NF;

  // ---- integrated edge role: issue loads EARLY (in flight during staging) ----
  int4 s4, d4, t4;
  bool doE = (NF == 0) && (t < 128);
  int ebb = 0;
  if (doE){
    ebb = bi & 7;
    int e4 = (bi >> 3)*128 + t;          // 128 int4s/block * 128 chunks = EE/4 per batch
    const int* base = ei + (long)(b0+ebb)*2*EE;
    s4 = ((const int4*)base)[e4];
    d4 = ((const int4*)(base + EE))[e4];
    t4 = ((const int4*)(ety + (long)(b0+ebb)*EE))[e4];
  }

  // ---- projection 22->64 + linear0 64x64 + sdot ----
  __attribute__((aligned(16))) __shared__ float wlT[64*68];
  __attribute__((aligned(16))) __shared__ float nfl[32*24];
  __attribute__((aligned(16))) __shared__ float xs[32*68];

  if (lb == 0 && t < 48){
    int ll = t >> 4, r = t & 15;
    if (r < 12){
      int ty = r >> 2, hd2 = r & 3;
      float s = 0.f;
      #pragma unroll
      for (int k=0;k<16;k++)
        s += ld(eemb, ll*48 + ty*16 + k) * ld(a_edge, ll*64 + hd2*16 + k);
      ebt[t] = s * LOG2E;     // ebt[ll*16 + ty*4 + hd]
    }
  }
  {
    #pragma unroll
    for (int idx = t; idx < 1024; idx += 256){
      int row = idx >> 4, chunk = idx & 15;
      float4 wv = *((const float4*)((const float*)W + row*64 + chunk*4));
      *((float4*)&wlT[row*68 + chunk*4]) = wv;
    }
  }
  {
    long nfbase = ((long)b0*NN + (long)lb*32)*22;
    for (int idx = t; idx < 704; idx += 256){
      int row = idx / 22, k = idx - row*22;
      nfl[row*24 + k] = ld(nf, nfbase + idx);
    }
  }

  int w = t >> 6;
  int c = t & 63;
  int hd = c >> 4, dd2 = c & 15;
  long n0 = (long)lb*32 + w*8;

  float wreg[22];
  #pragma unroll
  for (int k = 0; k < 22; k++) wreg[k] = ld(pw, c*22 + k);
  float bias = ld(pb, c);
  __syncthreads();

  // ---- integrated edge role: atomics + csr stores (latency hides under matmul) ----
  if (doE){
    int* cb = cursor + ebb*NN;
    int ss[4] = {s4.x & (NN-1), s4.y & (NN-1), s4.z & (NN-1), s4.w & (NN-1)};
    int dd[4] = {d4.x & (NN-1), d4.y & (NN-1), d4.z & (NN-1), d4.w & (NN-1)};
    int tt[4] = {t4.x, t4.y, t4.z, t4.w};
    #pragma unroll
    for (int i=0;i<4;i++){
      int ty = tt[i]; ty = (ty < 0) ? 0 : (ty > 2 ? 2 : ty);
      int p = atomicAdd(&cb[dd[i]], 1);
      if (p < 64) csr[((long)(ebb*NN) + dd[i])*64 + p] = (unsigned short)(ss[i] | (ty << 12));
    }
  }
  if (n0 >= nb*NN) return;

  #pragma unroll
  for (int i=0;i<8;i++){
    const float* nr = nfl + (w*8+i)*24;
    float a = bias;
    #pragma unroll
    for (int kc = 0; kc < 5; kc++){
      float4 nv = *((const float4*)&nr[kc*4]);
      a += nv.x*wreg[kc*4] + nv.y*wreg[kc*4+1] + nv.z*wreg[kc*4+2] + nv.w*wreg[kc*4+3];
    }
    a += nr[20]*wreg[20] + nr[21]*wreg[21];
    xs[(w*8+i)*68 + c] = a;
  }

  float acc[8] = {0.f,0.f,0.f,0.f,0.f,0.f,0.f,0.f};
  const float* xw = xs + (w*8)*68;
  const float* wr2 = wlT + c*68;
  #pragma unroll 4
  for (int kk=0;kk<16;kk++){
    float4 wv = *((const float4*)&wr2[kk*4]);
    #pragma unroll
    for (int i=0;i<8;i++){
      float4 xv = *((const float4*)&xw[i*68 + kk*4]);
      acc[i] += xv.x*wv.x + xv.y*wv.y + xv.z*wv.z + xv.w*wv.w;
    }
  }

  float cas = ld(a_src, c) * LOG2E;
  float cad = ld(a_dst, c) * LOG2E;
  #pragma unroll
  for (int i=0;i<8;i++){
    h[(n0+i)*64 + c] = acc[i];
    float ps = acc[i]*cas, pd = acc[i]*cad;
    #pragma unroll
    for (int o=8;o>=1;o>>=1){
      ps += __shfl_xor(ps,o,64);
      pd += __shfl_xor(pd,o,64);
    }
    if (dd2 == 0){
      sdot[(n0+i)*8 + hd]     = ps;
      sdot[(n0+i)*8 + 4 + hd] = pd;
    }
  }
}

// SIMD-transposed GAT aggregation for one node (wave-cooperative)
__device__ __forceinline__ float gat_node(const float* __restrict__ hb,
    const float* __restrict__ sb, const unsigned short* __restrict__ cb, int dg,
    float sdP, float ebP0, float ebP1, float ebP2,
    float hdst, int c, int hd,
    const void* lng, const void* lnb, int l){
  int hL = c & 3;
  float denP = 0.f, acc = 0.f;
  int npass = (dg + 15) >> 4;
  for (int p = 0; p < npass; p++){
    int eidx = (p << 4) + (c >> 2);
    int pk = cb[eidx];
    int src = pk & 4095, ty = (pk >> 12) & 3;
    float av = sb[src*8 + hL] + sdP + (ty==0?ebP0:(ty==1?ebP1:ebP2));
    av = fmaxf(av, 0.2f*av);
    float ev = exp2f(av);
    if (eidx >= dg) ev = 0.f;
    denP += ev;
    int jmax = dg - (p << 4); if (jmax > 16) jmax = 16;
    #pragma unroll 4
    for (int j = 0; j < jmax; j++){
      float evj = __shfl(ev, j*4 + hd, 64);
      int sj = __builtin_amdgcn_readlane(pk, j*4) & 4095;
      acc += hb[(long)sj*64 + c] * evj;
    }
  }
  #pragma unroll
  for (int o=4;o<=32;o<<=1) denP += __shfl_xor(denP, o, 64);
  float den = __shfl(denP, hd, 64);
  float y = acc / (den + 1e-10f) + hdst;

  float s = y;
  #pragma unroll
  for (int o=32;o>=1;o>>=1) s += __shfl_xor(s, o, 64);
  float mean = s * (1.f/64.f);
  float d = y - mean;
  float vs = d*d;
  #pragma unroll
  for (int o=32;o>=1;o>>=1) vs += __shfl_xor(vs, o, 64);
  float var = vs * (1.f/64.f);
  float outv = d * rsqrtf(var + 1e-5f) * ld(lng, l*64+c) + ld(lnb, l*64+c);
  return gelu_f(outv);
}

// shared tail of the GAT+linear fusion: write h/sdot for layer l+1 (global)
__device__ __forceinline__ void gat_linear_tail(float g, float* xs, const float* wlT,
    const void* a_src, const void* a_dst, float* __restrict__ hOut,
    float* __restrict__ sdOut, long wave, int wloc, int c, int hd, int dd, int l){
  xs[wloc*68 + c] = g;
  float ha = 0.f;
  const float* xw = xs + wloc*68;
  const float* wr = wlT + c*68;
  #pragma unroll 4
  for (int kk=0;kk<16;kk++){
    float4 xv = *((const float4*)&xw[kk*4]);
    float4 wv = *((const float4*)&wr[kk*4]);
    ha += xv.x*wv.x + xv.y*wv.y + xv.z*wv.z + xv.w*wv.w;
  }
  hOut[wave*64 + c] = ha;
  float cas = ld(a_src, (long)(l+1)*64 + c) * LOG2E;
  float cad = ld(a_dst, (long)(l+1)*64 + c) * LOG2E;
  float ps = ha*cas, pd = ha*cad;
  #pragma unroll
  for (int o=8;o>=1;o>>=1){
    ps += __shfl_xor(ps,o,64);
    pd += __shfl_xor(pd,o,64);
  }
  if (dd == 0){
    sdOut[wave*8 + hd]     = ps;
    sdOut[wave*8 + 4 + hd] = pd;
  }
}

// GAT(0)+linear(1), PRUNED to the 2-HOP cone of the center node.
__global__ __launch_bounds__(256) void k_gatcone(
    const float* __restrict__ hIn, const float* __restrict__ sdIn,
    const float* __restrict__ ebt,
    const int* __restrict__ cursor, const unsigned short* __restrict__ csr,
    const void* __restrict__ lng, const void* __restrict__ lnb,
    const void* __restrict__ W,
    const void* __restrict__ a_src, const void* __restrict__ a_dst,
    float* __restrict__ hOut, float* __restrict__ sdOut,
    int l, int nb){
  __attribute__((aligned(16))) __shared__ float wlT[64*68];
  __attribute__((aligned(16))) __shared__ float xs[4*68];
  int t = threadIdx.x;
  int wloc = t >> 6;
  int b  = (int)blockIdx.x % nb;
  int ib = (int)blockIdx.x / nb;
  long wcen = (long)b*NN + NN/2;
  int dgc = cursor[wcen];
  dgc = (dgc < 0) ? 0 : (dgc > 64 ? 64 : dgc);
  int e0 = ib*4;
  if (e0/65 > dgc) return;           // block-uniform: all 4 waves out of range
  {
    #pragma unroll
    for (int idx = t; idx < 1024; idx += 256){
      int row = idx >> 4, chunk = idx & 15;
      float4 wv = *((const float4*)((const float*)W + (long)(l+1)*4096 + row*64 + chunk*4));
      *((float4*)&wlT[row*68 + chunk*4]) = wv;
    }
  }
  __syncthreads();

  int e = e0 + wloc;
  int i = e / 65, j = e - i*65;
  long wave = -1;
  if (e < 4225 && i <= dgc){
    long vi = (i == 0) ? wcen : (long)b*NN + (csr[wcen*64 + (i-1)] & 4095);
    int dgi = cursor[vi];
    dgi = (dgi < 0) ? 0 : (dgi > 64 ? 64 : dgi);
    if (j == 0)            wave = vi;
    else if (j <= dgi)     wave = (long)b*NN + (csr[vi*64 + (j-1)] & 4095);
  }
  if (wave < 0) return;              // wave-uniform exit

  int c  = t & 63;
  int hd = c >> 4, dd = c & 15, hL = c & 3;

  float ebP0 = ebt[l*16 + 0 + hL];
  float ebP1 = ebt[l*16 + 4 + hL];
  float ebP2 = ebt[l*16 + 8 + hL];
  float sdP  = sdIn[wave*8 + 4 + hL];
  float hdst = hIn[wave*64 + c];
  int dg = __builtin_amdgcn_readfirstlane(cursor[wave]);
  dg = (dg < 0) ? 0 : (dg > 64 ? 64 : dg);
  const unsigned short* cb = csr + wave*64;
  const float* hb = hIn + (long)b*NN*64;
  const float* sb = sdIn + (long)b*NN*8;

  float g = gat_node(hb, sb, cb, dg, sdP, ebP0, ebP1, ebP2, hdst, c, hd, lng, lnb, l);
  gat_linear_tail(g, xs, wlT, a_src, a_dst, hOut, sdOut, wave, wloc, c, hd, dd, l);
}

// Layers 2+3 merged: one 1024-thread block per batch.
__global__ __launch_bounds__(1024) void k_gat23(
    const float* __restrict__ hIn, const float* __restrict__ sdIn,   // layer-1 h/sdot (hB/sdotB)
    const float* __restrict__ ebt,
    const int* __restrict__ cursor, const unsigned short* __restrict__ csr,
    const void* __restrict__ lng, const void* __restrict__ lnb,
    const void* __restrict__ W,
    const void* __restrict__ a_src, const void* __restrict__ a_dst,
    float* __restrict__ cemb, int b0, int nb){
  __attribute__((aligned(16))) __shared__ float wlT[64*68];   // W[2] row-per-lane
  __attribute__((aligned(16))) __shared__ float xsL[16*68];
  __attribute__((aligned(16))) __shared__ float h2L[65*68];   // layer-2 h for S1 entries
  __shared__ float sd2L[65*9];                                // layer-2 sdot for S1 entries
  int t = threadIdx.x;
  int b = (int)blockIdx.x;
  if (b >= nb) return;
  { // stage W[2]: 1024 float4s, one per thread
    int row = t >> 4, chunk = t & 15;
    float4 wv = *((const float4*)((const float*)W + 2*4096 + row*64 + chunk*4));
    *((float4*)&wlT[row*68 + chunk*4]) = wv;
  }
  long wcen = (long)b*NN + NN/2;
  int dgc = cursor[wcen];
  dgc = (dgc < 0) ? 0 : (dgc > 64 ? 64 : dgc);
  int wv = t >> 6, c = t & 63;
  int hd = c >> 4, dd = c & 15, hL = c & 3;
  const float* hb = hIn + (long)b*NN*64;
  const float* sb = sdIn + (long)b*NN*8;
  float eb10 = ebt[16 + 0 + hL], eb11 = ebt[16 + 4 + hL], eb12 = ebt[16 + 8 + hL];
  float cas2 = ld(a_src, 2*64 + c) * LOG2E;
  float cad2 = ld(a_dst, 2*64 + c) * LOG2E;
  __syncthreads();

  // ---- phase 1: S1 nodes, layer-1 GAT + linear(2) -> LDS ----
  for (int r = 0; r < 5; r++){
    int e = r*16 + wv;                     // wave-uniform entry id
    if (e < 65 && e <= dgc){
      long wave = (e == 0) ? wcen : (long)b*NN + (csr[wcen*64 + (e-1)] & 4095);
      float sdP  = sdIn[wave*8 + 4 + hL];
      float hdst = hIn[wave*64 + c];
      int dg = __builtin_amdgcn_readfirstlane(cursor[wave]);
      dg = (dg < 0) ? 0 : (dg > 64 ? 64 : dg);
      const unsigned short* cb = csr + wave*64;
      float g = gat_node(hb, sb, cb, dg, sdP, eb10, eb11, eb12, hdst, c, hd, lng, lnb, 1);
      xsL[wv*68 + c] = g;
      float ha = 0.f;
      const float* xw = xsL + wv*68;
      const float* wr = wlT + c*68;
      #pragma unroll 4
      for (int kk=0;kk<16;kk++){
        float4 xv = *((const float4*)&xw[kk*4]);
        float4 wvv = *((const float4*)&wr[kk*4]);
        ha += xv.x*wvv.x + xv.y*wvv.y + xv.z*wvv.z + xv.w*wvv.w;
      }
      h2L[e*68 + c] = ha;
      float ps = ha*cas2, pd = ha*cad2;
      #pragma unroll
      for (int o=8;o>=1;o>>=1){
        ps += __shfl_xor(ps,o,64);
        pd += __shfl_xor(pd,o,64);
      }
      if (dd == 0){
        sd2L[e*9 + hd]     = ps;
        sd2L[e*9 + 4 + hd] = pd;
      }
    }
  }
  __syncthreads();

  // ---- phase 2: center node, layer-2 GAT, all inputs in LDS ----
  if (t < 64){
    float eb0 = ebt[32 + 0 + hL], eb1 = ebt[32 + 4 + hL], eb2 = ebt[32 + 8 + hL];
    float sdP  = sd2L[4 + hL];             // center's dst-dot (entry 0)
    float hdst = h2L[c];                   // center's h2 (entry 0)
    int dg = dgc;
    const unsigned short* cb = csr + wcen*64;
    float denP = 0.f, acc = 0.f;
    int npass = (dg + 15) >> 4;
    for (int p = 0; p < npass; p++){
      int eidx = (p << 4) + (c >> 2);      // slot in csr[center], <= 63
      int pk = cb[eidx];
      int ty = (pk >> 12) & 3;
      float av = sd2L[(eidx+1)*9 + hL] + sdP + (ty==0?eb0:(ty==1?eb1:eb2));
      av = fmaxf(av, 0.2f*av);
      float ev = exp2f(av);
      if (eidx >= dg) ev = 0.f;
      denP += ev;
      int jmax = dg - (p << 4); if (jmax > 16) jmax = 16;
      #pragma unroll 4
      for (int j = 0; j < jmax; j++){
        float evj = __shfl(ev, j*4 + hd, 64);
        acc += h2L[(p*16 + j + 1)*68 + c] * evj;   // slot -> LDS entry j+1
      }
    }
    #pragma unroll
    for (int o=4;o<=32;o<<=1) denP += __shfl_xor(denP, o, 64);
    float den = __shfl(denP, hd, 64);
    float y = acc / (den + 1e-10f) + hdst;
    float s = y;
    #pragma unroll
    for (int o=32;o>=1;o>>=1) s += __shfl_xor(s, o, 64);
    float mean = s * (1.f/64.f);
    float d = y - mean;
    float vs = d*d;
    #pragma unroll
    for (int o=32;o>=1;o>>=1) vs += __shfl_xor(vs, o, 64);
    float var = vs * (1.f/64.f);
    float outv = d * rsqrtf(var + 1e-5f) * ld(lng, 2*64+c) + ld(lnb, 2*64+c);
    cemb[(b0+b)*64 + c] = gelu_f(outv);
  }
}

// enc1 with in-block fused construction (reads center embedding from cemb)
__global__ __launch_bounds__(256) void k_enc1(const float* __restrict__ ctr,
    const void* rnafm, const void* edelta, const void* hand,
    const void* gow, const void* gob,
    const void* e1w, const void* e1b, float* __restrict__ g1){
  __shared__ float fb[1384];
  __shared__ float femb[64];
  int b = blockIdx.x, t = threadIdx.x;
  for (int i=t;i<640;i+=256){
    fb[i]     = ld(rnafm,  b*640+i);
    fb[704+i] = ld(edelta, b*640+i);
  }
  if (t<40) fb[1344+t] = ld(hand, b*40+t);
  if (t>=64 && t<128){
    int cc = t-64;
    femb[cc] = ctr[b*64+cc];
  }
  __syncthreads();
  if (t<64){
    float acc = ld(gob, t);
    #pragma unroll 8
    for (int k=0;k<64;k++) acc += femb[k]*ld(gow, t*64+k);
    fb[640+t] = acc;
  }
  __syncthreads();
  int w = t >> 6, lane = t & 63;
  int c = blockIdx.y*4 + w;
  long wr = (long)c*1384;
  float acc = 0.f;
  #pragma unroll 7
  for (int i=0;i<21;i++){
    int k = lane + 64*i;
    acc += fb[k]*ld(e1w, wr+k);
  }
  if (lane < 40){
    int k = 1344+lane;
    acc += fb[k]*ld(e1w, wr+k);
  }
  #pragma unroll
  for (int o=32;o>=1;o>>=1) acc += __shfl_xor(acc, o, 64);
  if (lane==0) g1[b*256+c] = gelu_f(acc + ld(e1b, c));
}

// enc2 with integrated LayerNorm
__global__ __launch_bounds__(256) void k_enc2(const float* __restrict__ g1,
    const void* lng, const void* lnb, const void* e2w, const void* e2b,
    float* __restrict__ shs, float* __restrict__ out){
  __shared__ float red[256];
  __shared__ float h1s[256];
  int b = blockIdx.x, t = threadIdx.x;
  float g = g1[b*256+t];
  red[t] = g; __syncthreads();
  for (int s=128;s>=1;s>>=1){ if (t<s) red[t]+=red[t+s]; __syncthreads(); }
  float mean = red[0]*(1.f/256.f); __syncthreads();
  red[t] = (g-mean)*(g-mean); __syncthreads();
  for (int s=128;s>=1;s>>=1){ if (t<s) red[t]+=red[t+s]; __syncthreads(); }
  float var = red[0]*(1.f/256.f);
  h1s[t] = (g-mean)*rsqrtf(var+1e-5f)*ld(lng, t) + ld(lnb, t);
  __syncthreads();
  int w = t >> 6, lane = t & 63;
  int c = blockIdx.y*4 + w;
  long wr = (long)c*256;
  float acc = 0.f;
  #pragma unroll
  for (int i=0;i<4;i++){
    int k = lane + 64*i;
    acc += h1s[k]*ld(e2w, wr+k);
  }
  #pragma unroll
  for (int o=32;o>=1;o>>=1) acc += __shfl_xor(acc, o, 64);
  if (lane==0){
    float s = gelu_f(acc + ld(e2b, c));
    shs[b*128+c] = s;
    out[96 + b*128 + c] = s;
  }
}

__global__ __launch_bounds__(256) void k_mid(const float* __restrict__ shs,
    const void* a1w, const void* a1b, const void* c1w, const void* c1b,
    float* __restrict__ a1s, float* __restrict__ c1s){
  int b = blockIdx.x;
  int w = threadIdx.x >> 6, lane = threadIdx.x & 63;
  int idx = blockIdx.y*4 + w;
  const float* sb = shs + b*128;
  if (idx < 160){
    long wr = (long)idx*128;
    float acc = sb[lane]*ld(a1w, wr+lane) + sb[lane+64]*ld(a1w, wr+lane+64);
    #pragma unroll
    for (int o=32;o>=1;o>>=1) acc += __shfl_xor(acc, o, 64);
    if (lane==0) a1s[b*160+idx] = gelu_f(acc + ld(a1b, idx));
  } else {
    int c = idx - 160;
    long wr = (long)c*128;
    float acc = sb[lane]*ld(c1w, wr+lane) + sb[lane+64]*ld(c1w, wr+lane+64);
    #pragma unroll
    for (int o=32;o>=1;o>>=1) acc += __shfl_xor(acc, o, 64);
    if (lane==0) c1s[b*64+c] = gelu_f(acc + ld(c1b, c));
  }
}

__global__ __launch_bounds__(64) void k_fin(const float* __restrict__ shs,
    const float* __restrict__ a1s, const float* __restrict__ c1s,
    const void* binw, const void* binb, const void* a2w, const void* a2b,
    const void* c2w, const void* c2b,
    float* __restrict__ out){
  int b = blockIdx.x, t = threadIdx.x;
  {
    float p = shs[b*128+t]*ld(binw, t) + shs[b*128+t+64]*ld(binw, t+64);
    #pragma unroll
    for (int o=32;o>=1;o>>=1) p += __shfl_xor(p, o, 64);
    if (t==0) out[b] = p + ld(binb, 0);
  }
  if (t<5){
    float acc = ld(a2b, t);
    for (int i=0;i<32;i++) acc += a1s[b*160 + t*32+i]*ld(a2w, t*32+i);
    out[8 + b*5 + t] = acc;
  }
  if (t>=8 && t<14){
    int o = t-8;
    float acc = ld(c2b, o);
    for (int j=0;j<64;j++) acc += c1s[b*64+j]*ld(c2w, o*64+j);
    out[48 + b*6 + o] = acc;
  }
}

extern "C" void kernel_launch(void* const* d_in, const int* in_sizes, int n_in,
                              void* d_out, int out_size, void* d_ws, size_t ws_size,
                              hipStream_t stream) {
  const int* ei  = (const int*)d_in[4];
  const int* ety = (const int*)d_in[5];

  size_t need_full = 2048 + 512
                   + (size_t)4*((size_t)BB*NN)
                   + (size_t)4*((size_t)BB*NN*64)
                   + (size_t)4*3*((size_t)BB*NN*64)
                   + (size_t)4*2*((size_t)BB*NN*8)
                   + (size_t)4*(8*256 + 8*128 + 8*160 + 8*64 + 64);
  int nb = (ws_size >= need_full + (1u<<20)) ? BB : 1;

  char* ws = (char*)d_ws;
  float* cemb    = (float*)ws;
  float* ebt     = (float*)(ws + 2048 + 256);
  int*   cursor  = (int*)(ws + 2048 + 512);
  int*   ticket  = cursor + (size_t)nb*NN;                       // 64 ints (layout kept)
  unsigned short* csr = (unsigned short*)(ticket + 64);          // nb*NN*64 ushorts
  float* hA      = (float*)((char*)csr + (size_t)nb*NN*64*2);
  float* hB      = hA + (size_t)nb*NN*64;
  float* sdotA   = hB + (size_t)nb*NN*64;
  float* sdotB   = sdotA + (size_t)nb*NN*8;
  float* g1      = sdotB + (size_t)nb*NN*8;
  float* shs     = g1 + 8*256;
  float* a1s     = shs + 8*128;
  float* c1s     = a1s + 8*160;

  for (int b0 = 0; b0 < BB; b0 += nb){
    hipMemsetAsync(cursor, 0, ((size_t)nb*NN + 64)*sizeof(int), stream);
    int NL = nb*NN/32;
    int NF = (nb == BB) ? 0 : nb*(EE/1024);   // integrated mode when nb==8
    hipLaunchKernelGGL(k_pre, dim3(NF+NL), dim3(256), 0, stream,
                       d_in[3], d_in[6], d_in[7],
                       d_in[8], d_in[9], d_in[10], d_in[11], d_in[12],
                       ei, ety, hA, sdotA, ebt, cursor, csr, b0, nb, NF);
    hipLaunchKernelGGL(k_gatcone, dim3(nb*1057), dim3(256), 0, stream,
                       hA, sdotA, ebt, cursor, csr, d_in[13], d_in[14],
                       d_in[8], d_in[9], d_in[10], hB, sdotB, 0, nb);
    hipLaunchKernelGGL(k_gat23, dim3(nb), dim3(1024), 0, stream,
                       hB, sdotB, ebt, cursor, csr, d_in[13], d_in[14],
                       d_in[8], d_in[9], d_in[10], cemb, b0, nb);
  }

  hipLaunchKernelGGL(k_enc1, dim3(BB, 64), dim3(256), 0, stream,
                     cemb,
                     d_in[0], d_in[1], d_in[2], d_in[15], d_in[16],
                     d_in[17], d_in[18], g1);
  hipLaunchKernelGGL(k_enc2, dim3(BB, 32), dim3(256), 0, stream,
                     g1, d_in[19], d_in[20], d_in[21], d_in[22], shs, (float*)d_out);
  hipLaunchKernelGGL(k_mid,  dim3(BB, 56), dim3(256), 0, stream,
                     shs, d_in[25], d_in[26], d_in[29], d_in[30], a1s, c1s);
  hipLaunchKernelGGL(k_fin,  dim3(BB), dim3(64), 0, stream,
                     shs, a1s, c1s, d_in[23], d_in[24], d_in[27], d_in[28],
                     d_in[31], d_in[32], (float*)d_out);
}

// Round 11
// 201.970 us; speedup vs baseline: 1.2327x; 1.0432x over previous
//
#include <hip/hip_runtime.h>
#include <hip/hip_bf16.h>
#include <math.h>

#define BB 8
#define NN 4096
#define EE 65536
#define LOG2E 1.4426950408889634f

__device__ __forceinline__ float my_erf(float x){
  float ax = fabsf(x);
  float tt = 1.f/(1.f + 0.3275911f*ax);
  float poly = ((((1.061405429f*tt - 1.453152027f)*tt + 1.421413741f)*tt
                 - 0.284496736f)*tt + 0.254829592f)*tt;
  float y = 1.f - poly*expf(-ax*ax);
  return x >= 0.f ? y : -y;
}
__device__ __forceinline__ float gelu_f(float x){ return 0.5f*x*(1.0f + my_erf(x*0.7071067811865476f)); }
__device__ __forceinline__ float ld(const void* p, long i){ return ((const float*)p)[i]; }

// k_pre: layer-0 projection+linear (all nodes) + cone pass A.
// NF>0  (nb==1 fallback): blocks [0,NF) do the OLD full CSR fill.
// NF==0 (nb==8): integrated pass A — threads t<128 scan 512 edges of batch
//   blockIdx&7; only edges with dst==center fill csr[center] (+bm1[src] mark).
//   ~16 atomics/batch instead of 65K: kills the L2-atomic storm.
__global__ __launch_bounds__(256) void k_pre(
    const void* __restrict__ nf, const void* __restrict__ pw, const void* __restrict__ pb,
    const void* __restrict__ W, const void* __restrict__ a_src, const void* __restrict__ a_dst,
    const void* __restrict__ a_edge, const void* __restrict__ eemb,
    const int* __restrict__ ei, const int* __restrict__ ety,
    float* __restrict__ h, float* __restrict__ sdot, float* __restrict__ ebt,
    int* __restrict__ cursor, unsigned short* __restrict__ csr,
    unsigned* __restrict__ bm1, int b0, int nb, int NF){
  int t = threadIdx.x;
  int bi = (int)blockIdx.x;
  if (NF > 0 && bi < NF){
    // ---- nb==1 path: full CSR fill, 4 edges/thread ----
    int bpb = NF / nb;
    int b = bi / bpb, q = bi - b*bpb;
    int e4 = q*256 + t;
    const int* base = ei + (long)(b0+b)*2*EE;
    int4 s4 = ((const int4*)base)[e4];
    int4 d4 = ((const int4*)(base + EE))[e4];
    int4 t4 = ((const int4*)(ety + (long)(b0+b)*EE))[e4];
    int* cb = cursor + b*NN;
    int ss[4] = {s4.x & (NN-1), s4.y & (NN-1), s4.z & (NN-1), s4.w & (NN-1)};
    int dd[4] = {d4.x & (NN-1), d4.y & (NN-1), d4.z & (NN-1), d4.w & (NN-1)};
    int tt[4] = {t4.x, t4.y, t4.z, t4.w};
    #pragma unroll
    for (int i=0;i<4;i++){
      int ty = tt[i]; ty = (ty < 0) ? 0 : (ty > 2 ? 2 : ty);
      int p = atomicAdd(&cb[dd[i]], 1);
      if (p < 64) csr[((long)(b*NN) + dd[i])*64 + p] = (unsigned short)(ss[i] | (ty << 12));
    }
    return;
  }
  int lb = bi - NF;

  // ---- pass-A edge role: issue loads early ----
  int4 s4, d4, t4;
  bool doE = (NF == 0) && (t < 128);
  int ebb = 0;
  if (doE){
    ebb = bi & 7;
    int e4 = (bi >> 3)*128 + t;
    const int* base = ei + (long)(b0+ebb)*2*EE;
    s4 = ((const int4*)base)[e4];
    d4 = ((const int4*)(base + EE))[e4];
    t4 = ((const int4*)(ety + (long)(b0+ebb)*EE))[e4];
  }

  __attribute__((aligned(16))) __shared__ float wlT[64*68];
  __attribute__((aligned(16))) __shared__ float nfl[32*24];
  __attribute__((aligned(16))) __shared__ float xs[32*68];

  if (lb == 0 && t < 48){
    int ll = t >> 4, r = t & 15;
    if (r < 12){
      int ty = r >> 2, hd2 = r & 3;
      float s = 0.f;
      #pragma unroll
      for (int k=0;k<16;k++)
        s += ld(eemb, ll*48 + ty*16 + k) * ld(a_edge, ll*64 + hd2*16 + k);
      ebt[t] = s * LOG2E;
    }
  }
  {
    #pragma unroll
    for (int idx = t; idx < 1024; idx += 256){
      int row = idx >> 4, chunk = idx & 15;
      float4 wv = *((const float4*)((const float*)W + row*64 + chunk*4));
      *((float4*)&wlT[row*68 + chunk*4]) = wv;
    }
  }
  {
    long nfbase = ((long)b0*NN + (long)lb*32)*22;
    for (int idx = t; idx < 704; idx += 256){
      int row = idx / 22, k = idx - row*22;
      nfl[row*24 + k] = ld(nf, nfbase + idx);
    }
  }

  int w = t >> 6;
  int c = t & 63;
  int hd = c >> 4, dd2 = c & 15;
  long n0 = (long)lb*32 + w*8;

  float wreg[22];
  #pragma unroll
  for (int k = 0; k < 22; k++) wreg[k] = ld(pw, c*22 + k);
  float bias = ld(pb, c);
  __syncthreads();

  // ---- pass A: only center-destined edges (rare) ----
  if (doE){
    int ss[4] = {s4.x & (NN-1), s4.y & (NN-1), s4.z & (NN-1), s4.w & (NN-1)};
    int dd[4] = {d4.x & (NN-1), d4.y & (NN-1), d4.z & (NN-1), d4.w & (NN-1)};
    int tt[4] = {t4.x, t4.y, t4.z, t4.w};
    #pragma unroll
    for (int i=0;i<4;i++){
      if (dd[i] == NN/2){
        int ty = tt[i]; ty = (ty < 0) ? 0 : (ty > 2 ? 2 : ty);
        int p = atomicAdd(&cursor[ebb*NN + NN/2], 1);
        if (p < 64) csr[((long)(ebb*NN) + NN/2)*64 + p] = (unsigned short)(ss[i] | (ty << 12));
        atomicOr(&bm1[ebb*128 + (ss[i] >> 5)], 1u << (ss[i] & 31));
      }
    }
  }
  if (n0 >= nb*NN) return;

  #pragma unroll
  for (int i=0;i<8;i++){
    const float* nr = nfl + (w*8+i)*24;
    float a = bias;
    #pragma unroll
    for (int kc = 0; kc < 5; kc++){
      float4 nv = *((const float4*)&nr[kc*4]);
      a += nv.x*wreg[kc*4] + nv.y*wreg[kc*4+1] + nv.z*wreg[kc*4+2] + nv.w*wreg[kc*4+3];
    }
    a += nr[20]*wreg[20] + nr[21]*wreg[21];
    xs[(w*8+i)*68 + c] = a;
  }

  float acc[8] = {0.f,0.f,0.f,0.f,0.f,0.f,0.f,0.f};
  const float* xw = xs + (w*8)*68;
  const float* wr2 = wlT + c*68;
  #pragma unroll 4
  for (int kk=0;kk<16;kk++){
    float4 wv = *((const float4*)&wr2[kk*4]);
    #pragma unroll
    for (int i=0;i<8;i++){
      float4 xv = *((const float4*)&xw[i*68 + kk*4]);
      acc[i] += xv.x*wv.x + xv.y*wv.y + xv.z*wv.z + xv.w*wv.w;
    }
  }

  float cas = ld(a_src, c) * LOG2E;
  float cad = ld(a_dst, c) * LOG2E;
  #pragma unroll
  for (int i=0;i<8;i++){
    h[(n0+i)*64 + c] = acc[i];
    float ps = acc[i]*cas, pd = acc[i]*cad;
    #pragma unroll
    for (int o=8;o>=1;o>>=1){
      ps += __shfl_xor(ps,o,64);
      pd += __shfl_xor(pd,o,64);
    }
    if (dd2 == 0){
      sdot[(n0+i)*8 + hd]     = ps;
      sdot[(n0+i)*8 + 4 + hd] = pd;
    }
  }
}

// cone fill passes (nb==8 only). mode 0 (B): dst in bm1, dst!=center ->
// fill csr[dst], mark bm2[src]. mode 1 (C): dst in bm2 and NOT bm1,
// dst!=center -> fill csr[dst]. Grid: 512 blocks; batch = blockIdx&7 (XCD-bound).
__global__ __launch_bounds__(256) void k_pass(
    const int* __restrict__ ei, const int* __restrict__ ety,
    const unsigned* __restrict__ bmA, unsigned* __restrict__ bmB,
    int* __restrict__ cursor, unsigned short* __restrict__ csr,
    int b0, int mode){
  int fi = (int)blockIdx.x;
  int b = fi & 7, q = fi >> 3;
  int e4 = q*256 + threadIdx.x;
  const int* base = ei + (long)(b0+b)*2*EE;
  int4 s4 = ((const int4*)base)[e4];
  int4 d4 = ((const int4*)(base + EE))[e4];
  int4 t4 = ((const int4*)(ety + (long)(b0+b)*EE))[e4];
  const unsigned* bA = bmA + b*128;
  unsigned* bB = bmB + b*128;
  int* cb = cursor + b*NN;
  int ss[4] = {s4.x & (NN-1), s4.y & (NN-1), s4.z & (NN-1), s4.w & (NN-1)};
  int dd[4] = {d4.x & (NN-1), d4.y & (NN-1), d4.z & (NN-1), d4.w & (NN-1)};
  int tt[4] = {t4.x, t4.y, t4.z, t4.w};
  #pragma unroll
  for (int i=0;i<4;i++){
    int d = dd[i];
    bool inA = (bA[d >> 5] >> (d & 31)) & 1u;
    bool hit;
    if (mode == 0) hit = inA && (d != NN/2);
    else {
      bool inB = (bB[d >> 5] >> (d & 31)) & 1u;
      hit = inB && !inA && (d != NN/2);
    }
    if (hit){
      int ty = tt[i]; ty = (ty < 0) ? 0 : (ty > 2 ? 2 : ty);
      int p = atomicAdd(&cb[d], 1);
      if (p < 64) csr[((long)(b*NN) + d)*64 + p] = (unsigned short)(ss[i] | (ty << 12));
      if (mode == 0) atomicOr(&bB[ss[i] >> 5], 1u << (ss[i] & 31));
    }
  }
}

// SIMD-transposed GAT aggregation for one node (wave-cooperative)
__device__ __forceinline__ float gat_node(const float* __restrict__ hb,
    const float* __restrict__ sb, const unsigned short* __restrict__ cb, int dg,
    float sdP, float ebP0, float ebP1, float ebP2,
    float hdst, int c, int hd,
    const void* lng, const void* lnb, int l){
  int hL = c & 3;
  float denP = 0.f, acc = 0.f;
  int npass = (dg + 15) >> 4;
  for (int p = 0; p < npass; p++){
    int eidx = (p << 4) + (c >> 2);
    int pk = cb[eidx];
    int src = pk & 4095, ty = (pk >> 12) & 3;
    float av = sb[src*8 + hL] + sdP + (ty==0?ebP0:(ty==1?ebP1:ebP2));
    av = fmaxf(av, 0.2f*av);
    float ev = exp2f(av);
    if (eidx >= dg) ev = 0.f;
    denP += ev;
    int jmax = dg - (p << 4); if (jmax > 16) jmax = 16;
    #pragma unroll 4
    for (int j = 0; j < jmax; j++){
      float evj = __shfl(ev, j*4 + hd, 64);
      int sj = __builtin_amdgcn_readlane(pk, j*4) & 4095;
      acc += hb[(long)sj*64 + c] * evj;
    }
  }
  #pragma unroll
  for (int o=4;o<=32;o<<=1) denP += __shfl_xor(denP, o, 64);
  float den = __shfl(denP, hd, 64);
  float y = acc / (den + 1e-10f) + hdst;

  float s = y;
  #pragma unroll
  for (int o=32;o>=1;o>>=1) s += __shfl_xor(s, o, 64);
  float mean = s * (1.f/64.f);
  float d = y - mean;
  float vs = d*d;
  #pragma unroll
  for (int o=32;o>=1;o>>=1) vs += __shfl_xor(vs, o, 64);
  float var = vs * (1.f/64.f);
  float outv = d * rsqrtf(var + 1e-5f) * ld(lng, l*64+c) + ld(lnb, l*64+c);
  return gelu_f(outv);
}

// shared tail of the GAT+linear fusion: write h/sdot for layer l+1 (global)
__device__ __forceinline__ void gat_linear_tail(float g, float* xs, const float* wlT,
    const void* a_src, const void* a_dst, float* __restrict__ hOut,
    float* __restrict__ sdOut, long wave, int wloc, int c, int hd, int dd, int l){
  xs[wloc*68 + c] = g;
  float ha = 0.f;
  const float* xw = xs + wloc*68;
  const float* wr = wlT + c*68;
  #pragma unroll 4
  for (int kk=0;kk<16;kk++){
    float4 xv = *((const float4*)&xw[kk*4]);
    float4 wv = *((const float4*)&wr[kk*4]);
    ha += xv.x*wv.x + xv.y*wv.y + xv.z*wv.z + xv.w*wv.w;
  }
  hOut[wave*64 + c] = ha;
  float cas = ld(a_src, (long)(l+1)*64 + c) * LOG2E;
  float cad = ld(a_dst, (long)(l+1)*64 + c) * LOG2E;
  float ps = ha*cas, pd = ha*cad;
  #pragma unroll
  for (int o=8;o>=1;o>>=1){
    ps += __shfl_xor(ps,o,64);
    pd += __shfl_xor(pd,o,64);
  }
  if (dd == 0){
    sdOut[wave*8 + hd]     = ps;
    sdOut[wave*8 + 4 + hd] = pd;
  }
}

// GAT(0)+linear(1), PRUNED to the 2-HOP cone of the center node.
__global__ __launch_bounds__(256) void k_gatcone(
    const float* __restrict__ hIn, const float* __restrict__ sdIn,
    const float* __restrict__ ebt,
    const int* __restrict__ cursor, const unsigned short* __restrict__ csr,
    const void* __restrict__ lng, const void* __restrict__ lnb,
    const void* __restrict__ W,
    const void* __restrict__ a_src, const void* __restrict__ a_dst,
    float* __restrict__ hOut, float* __restrict__ sdOut,
    int l, int nb){
  __attribute__((aligned(16))) __shared__ float wlT[64*68];
  __attribute__((aligned(16))) __shared__ float xs[4*68];
  int t = threadIdx.x;
  int wloc = t >> 6;
  int b  = (int)blockIdx.x % nb;
  int ib = (int)blockIdx.x / nb;
  long wcen = (long)b*NN + NN/2;
  int dgc = cursor[wcen];
  dgc = (dgc < 0) ? 0 : (dgc > 64 ? 64 : dgc);
  int e0 = ib*4;
  if (e0/65 > dgc) return;
  {
    #pragma unroll
    for (int idx = t; idx < 1024; idx += 256){
      int row = idx >> 4, chunk = idx & 15;
      float4 wv = *((const float4*)((const float*)W + (long)(l+1)*4096 + row*64 + chunk*4));
      *((float4*)&wlT[row*68 + chunk*4]) = wv;
    }
  }
  __syncthreads();

  int e = e0 + wloc;
  int i = e / 65, j = e - i*65;
  long wave = -1;
  if (e < 4225 && i <= dgc){
    long vi = (i == 0) ? wcen : (long)b*NN + (csr[wcen*64 + (i-1)] & 4095);
    int dgi = cursor[vi];
    dgi = (dgi < 0) ? 0 : (dgi > 64 ? 64 : dgi);
    if (j == 0)            wave = vi;
    else if (j <= dgi)     wave = (long)b*NN + (csr[vi*64 + (j-1)] & 4095);
  }
  if (wave < 0) return;

  int c  = t & 63;
  int hd = c >> 4, dd = c & 15, hL = c & 3;

  float ebP0 = ebt[l*16 + 0 + hL];
  float ebP1 = ebt[l*16 + 4 + hL];
  float ebP2 = ebt[l*16 + 8 + hL];
  float sdP  = sdIn[wave*8 + 4 + hL];
  float hdst = hIn[wave*64 + c];
  int dg = __builtin_amdgcn_readfirstlane(cursor[wave]);
  dg = (dg < 0) ? 0 : (dg > 64 ? 64 : dg);
  const unsigned short* cb = csr + wave*64;
  const float* hb = hIn + (long)b*NN*64;
  const float* sb = sdIn + (long)b*NN*8;

  float g = gat_node(hb, sb, cb, dg, sdP, ebP0, ebP1, ebP2, hdst, c, hd, lng, lnb, l);
  gat_linear_tail(g, xs, wlT, a_src, a_dst, hOut, sdOut, wave, wloc, c, hd, dd, l);
}

// Layers 2+3 merged: one 1024-thread block per batch.
__global__ __launch_bounds__(1024) void k_gat23(
    const float* __restrict__ hIn, const float* __restrict__ sdIn,
    const float* __restrict__ ebt,
    const int* __restrict__ cursor, const unsigned short* __restrict__ csr,
    const void* __restrict__ lng, const void* __restrict__ lnb,
    const void* __restrict__ W,
    const void* __restrict__ a_src, const void* __restrict__ a_dst,
    float* __restrict__ cemb, int b0, int nb){
  __attribute__((aligned(16))) __shared__ float wlT[64*68];
  __attribute__((aligned(16))) __shared__ float xsL[16*68];
  __attribute__((aligned(16))) __shared__ float h2L[65*68];
  __shared__ float sd2L[65*9];
  int t = threadIdx.x;
  int b = (int)blockIdx.x;
  if (b >= nb) return;
  {
    int row = t >> 4, chunk = t & 15;
    float4 wv = *((const float4*)((const float*)W + 2*4096 + row*64 + chunk*4));
    *((float4*)&wlT[row*68 + chunk*4]) = wv;
  }
  long wcen = (long)b*NN + NN/2;
  int dgc = cursor[wcen];
  dgc = (dgc < 0) ? 0 : (dgc > 64 ? 64 : dgc);
  int wv = t >> 6, c = t & 63;
  int hd = c >> 4, dd = c & 15, hL = c & 3;
  const float* hb = hIn + (long)b*NN*64;
  const float* sb = sdIn + (long)b*NN*8;
  float eb10 = ebt[16 + 0 + hL], eb11 = ebt[16 + 4 + hL], eb12 = ebt[16 + 8 + hL];
  float cas2 = ld(a_src, 2*64 + c) * LOG2E;
  float cad2 = ld(a_dst, 2*64 + c) * LOG2E;
  __syncthreads();

  for (int r = 0; r < 5; r++){
    int e = r*16 + wv;
    if (e < 65 && e <= dgc){
      long wave = (e == 0) ? wcen : (long)b*NN + (csr[wcen*64 + (e-1)] & 4095);
      float sdP  = sdIn[wave*8 + 4 + hL];
      float hdst = hIn[wave*64 + c];
      int dg = __builtin_amdgcn_readfirstlane(cursor[wave]);
      dg = (dg < 0) ? 0 : (dg > 64 ? 64 : dg);
      const unsigned short* cb = csr + wave*64;
      float g = gat_node(hb, sb, cb, dg, sdP, eb10, eb11, eb12, hdst, c, hd, lng, lnb, 1);
      xsL[wv*68 + c] = g;
      float ha = 0.f;
      const float* xw = xsL + wv*68;
      const float* wr = wlT + c*68;
      #pragma unroll 4
      for (int kk=0;kk<16;kk++){
        float4 xv = *((const float4*)&xw[kk*4]);
        float4 wvv = *((const float4*)&wr[kk*4]);
        ha += xv.x*wvv.x + xv.y*wvv.y + xv.z*wvv.z + xv.w*wvv.w;
      }
      h2L[e*68 + c] = ha;
      float ps = ha*cas2, pd = ha*cad2;
      #pragma unroll
      for (int o=8;o>=1;o>>=1){
        ps += __shfl_xor(ps,o,64);
        pd += __shfl_xor(pd,o,64);
      }
      if (dd == 0){
        sd2L[e*9 + hd]     = ps;
        sd2L[e*9 + 4 + hd] = pd;
      }
    }
  }
  __syncthreads();

  if (t < 64){
    float eb0 = ebt[32 + 0 + hL], eb1 = ebt[32 + 4 + hL], eb2 = ebt[32 + 8 + hL];
    float sdP  = sd2L[4 + hL];
    float hdst = h2L[c];
    int dg = dgc;
    const unsigned short* cb = csr + wcen*64;
    float denP = 0.f, acc = 0.f;
    int npass = (dg + 15) >> 4;
    for (int p = 0; p < npass; p++){
      int eidx = (p << 4) + (c >> 2);
      int pk = cb[eidx];
      int ty = (pk >> 12) & 3;
      float av = sd2L[(eidx+1)*9 + hL] + sdP + (ty==0?eb0:(ty==1?eb1:eb2));
      av = fmaxf(av, 0.2f*av);
      float ev = exp2f(av);
      if (eidx >= dg) ev = 0.f;
      denP += ev;
      int jmax = dg - (p << 4); if (jmax > 16) jmax = 16;
      #pragma unroll 4
      for (int j = 0; j < jmax; j++){
        float evj = __shfl(ev, j*4 + hd, 64);
        acc += h2L[(p*16 + j + 1)*68 + c] * evj;
      }
    }
    #pragma unroll
    for (int o=4;o<=32;o<<=1) denP += __shfl_xor(denP, o, 64);
    float den = __shfl(denP, hd, 64);
    float y = acc / (den + 1e-10f) + hdst;
    float s = y;
    #pragma unroll
    for (int o=32;o>=1;o>>=1) s += __shfl_xor(s, o, 64);
    float mean = s * (1.f/64.f);
    float d = y - mean;
    float vs = d*d;
    #pragma unroll
    for (int o=32;o>=1;o>>=1) vs += __shfl_xor(vs, o, 64);
    float var = vs * (1.f/64.f);
    float outv = d * rsqrtf(var + 1e-5f) * ld(lng, 2*64+c) + ld(lnb, 2*64+c);
    cemb[(b0+b)*64 + c] = gelu_f(outv);
  }
}

// enc1 with in-block fused construction (reads center embedding from cemb)
__global__ __launch_bounds__(256) void k_enc1(const float* __restrict__ ctr,
    const void* rnafm, const void* edelta, const void* hand,
    const void* gow, const void* gob,
    const void* e1w, const void* e1b, float* __restrict__ g1){
  __shared__ float fb[1384];
  __shared__ float femb[64];
  int b = blockIdx.x, t = threadIdx.x;
  for (int i=t;i<640;i+=256){
    fb[i]     = ld(rnafm,  b*640+i);
    fb[704+i] = ld(edelta, b*640+i);
  }
  if (t<40) fb[1344+t] = ld(hand, b*40+t);
  if (t>=64 && t<128){
    int cc = t-64;
    femb[cc] = ctr[b*64+cc];
  }
  __syncthreads();
  if (t<64){
    float acc = ld(gob, t);
    #pragma unroll 8
    for (int k=0;k<64;k++) acc += femb[k]*ld(gow, t*64+k);
    fb[640+t] = acc;
  }
  __syncthreads();
  int w = t >> 6, lane = t & 63;
  int c = blockIdx.y*4 + w;
  long wr = (long)c*1384;
  float acc = 0.f;
  #pragma unroll 7
  for (int i=0;i<21;i++){
    int k = lane + 64*i;
    acc += fb[k]*ld(e1w, wr+k);
  }
  if (lane < 40){
    int k = 1344+lane;
    acc += fb[k]*ld(e1w, wr+k);
  }
  #pragma unroll
  for (int o=32;o>=1;o>>=1) acc += __shfl_xor(acc, o, 64);
  if (lane==0) g1[b*256+c] = gelu_f(acc + ld(e1b, c));
}

// enc2 with integrated LayerNorm
__global__ __launch_bounds__(256) void k_enc2(const float* __restrict__ g1,
    const void* lng, const void* lnb, const void* e2w, const void* e2b,
    float* __restrict__ shs, float* __restrict__ out){
  __shared__ float red[256];
  __shared__ float h1s[256];
  int b = blockIdx.x, t = threadIdx.x;
  float g = g1[b*256+t];
  red[t] = g; __syncthreads();
  for (int s=128;s>=1;s>>=1){ if (t<s) red[t]+=red[t+s]; __syncthreads(); }
  float mean = red[0]*(1.f/256.f); __syncthreads();
  red[t] = (g-mean)*(g-mean); __syncthreads();
  for (int s=128;s>=1;s>>=1){ if (t<s) red[t]+=red[t+s]; __syncthreads(); }
  float var = red[0]*(1.f/256.f);
  h1s[t] = (g-mean)*rsqrtf(var+1e-5f)*ld(lng, t) + ld(lnb, t);
  __syncthreads();
  int w = t >> 6, lane = t & 63;
  int c = blockIdx.y*4 + w;
  long wr = (long)c*256;
  float acc = 0.f;
  #pragma unroll
  for (int i=0;i<4;i++){
    int k = lane + 64*i;
    acc += h1s[k]*ld(e2w, wr+k);
  }
  #pragma unroll
  for (int o=32;o>=1;o>>=1) acc += __shfl_xor(acc, o, 64);
  if (lane==0){
    float s = gelu_f(acc + ld(e2b, c));
    shs[b*128+c] = s;
    out[96 + b*128 + c] = s;
  }
}

__global__ __launch_bounds__(256) void k_mid(const float* __restrict__ shs,
    const void* a1w, const void* a1b, const void* c1w, const void* c1b,
    float* __restrict__ a1s, float* __restrict__ c1s){
  int b = blockIdx.x;
  int w = threadIdx.x >> 6, lane = threadIdx.x & 63;
  int idx = blockIdx.y*4 + w;
  const float* sb = shs + b*128;
  if (idx < 160){
    long wr = (long)idx*128;
    float acc = sb[lane]*ld(a1w, wr+lane) + sb[lane+64]*ld(a1w, wr+lane+64);
    #pragma unroll
    for (int o=32;o>=1;o>>=1) acc += __shfl_xor(acc, o, 64);
    if (lane==0) a1s[b*160+idx] = gelu_f(acc + ld(a1b, idx));
  } else {
    int c = idx - 160;
    long wr = (long)c*128;
    float acc = sb[lane]*ld(c1w, wr+lane) + sb[lane+64]*ld(c1w, wr+lane+64);
    #pragma unroll
    for (int o=32;o>=1;o>>=1) acc += __shfl_xor(acc, o, 64);
    if (lane==0) c1s[b*64+c] = gelu_f(acc + ld(c1b, c));
  }
}

__global__ __launch_bounds__(64) void k_fin(const float* __restrict__ shs,
    const float* __restrict__ a1s, const float* __restrict__ c1s,
    const void* binw, const void* binb, const void* a2w, const void* a2b,
    const void* c2w, const void* c2b,
    float* __restrict__ out){
  int b = blockIdx.x, t = threadIdx.x;
  {
    float p = shs[b*128+t]*ld(binw, t) + shs[b*128+t+64]*ld(binw, t+64);
    #pragma unroll
    for (int o=32;o>=1;o>>=1) p += __shfl_xor(p, o, 64);
    if (t==0) out[b] = p + ld(binb, 0);
  }
  if (t<5){
    float acc = ld(a2b, t);
    for (int i=0;i<32;i++) acc += a1s[b*160 + t*32+i]*ld(a2w, t*32+i);
    out[8 + b*5 + t] = acc;
  }
  if (t>=8 && t<14){
    int o = t-8;
    float acc = ld(c2b, o);
    for (int j=0;j<64;j++) acc += c1s[b*64+j]*ld(c2w, o*64+j);
    out[48 + b*6 + o] = acc;
  }
}

extern "C" void kernel_launch(void* const* d_in, const int* in_sizes, int n_in,
                              void* d_out, int out_size, void* d_ws, size_t ws_size,
                              hipStream_t stream) {
  const int* ei  = (const int*)d_in[4];
  const int* ety = (const int*)d_in[5];

  size_t need_full = 2048 + 512 + 16384
                   + (size_t)4*((size_t)BB*NN)
                   + (size_t)4*((size_t)BB*NN*64)
                   + (size_t)4*3*((size_t)BB*NN*64)
                   + (size_t)4*2*((size_t)BB*NN*8)
                   + (size_t)4*(8*256 + 8*128 + 8*160 + 8*64 + 64);
  int nb = (ws_size >= need_full + (1u<<20)) ? BB : 1;

  char* ws = (char*)d_ws;
  float* cemb    = (float*)ws;
  float* ebt     = (float*)(ws + 2048 + 256);
  int*   cursor  = (int*)(ws + 2048 + 512);
  int*   ticket  = cursor + (size_t)nb*NN;                       // 64 ints (layout kept)
  unsigned* bm1  = (unsigned*)(ticket + 64);                     // 8*128 words
  unsigned* bm2  = bm1 + 8*128;                                  // 8*128 words
  unsigned short* csr = (unsigned short*)(bm2 + 8*128);          // nb*NN*64 ushorts
  float* hA      = (float*)((char*)csr + (size_t)nb*NN*64*2);
  float* hB      = hA + (size_t)nb*NN*64;
  float* sdotA   = hB + (size_t)nb*NN*64;
  float* sdotB   = sdotA + (size_t)nb*NN*8;
  float* g1      = sdotB + (size_t)nb*NN*8;
  float* shs     = g1 + 8*256;
  float* a1s     = shs + 8*128;
  float* c1s     = a1s + 8*160;

  for (int b0 = 0; b0 < BB; b0 += nb){
    // zero cursor + ticket + bitmaps in one memset (contiguous)
    hipMemsetAsync(cursor, 0, ((size_t)nb*NN + 64 + 2048)*sizeof(int), stream);
    int NL = nb*NN/32;
    int NF = (nb == BB) ? 0 : nb*(EE/1024);   // pass-A mode when nb==8
    hipLaunchKernelGGL(k_pre, dim3(NF+NL), dim3(256), 0, stream,
                       d_in[3], d_in[6], d_in[7],
                       d_in[8], d_in[9], d_in[10], d_in[11], d_in[12],
                       ei, ety, hA, sdotA, ebt, cursor, csr, bm1, b0, nb, NF);
    if (nb == BB){
      hipLaunchKernelGGL(k_pass, dim3(512), dim3(256), 0, stream,
                         ei, ety, bm1, bm2, cursor, csr, b0, 0);
      hipLaunchKernelGGL(k_pass, dim3(512), dim3(256), 0, stream,
                         ei, ety, bm1, bm2, cursor, csr, b0, 1);
    }
    hipLaunchKernelGGL(k_gatcone, dim3(nb*1057), dim3(256), 0, stream,
                       hA, sdotA, ebt, cursor, csr, d_in[13], d_in[14],
                       d_in[8], d_in[9], d_in[10], hB, sdotB, 0, nb);
    hipLaunchKernelGGL(k_gat23, dim3(nb), dim3(1024), 0, stream,
                       hB, sdotB, ebt, cursor, csr, d_in[13], d_in[14],
                       d_in[8], d_in[9], d_in[10], cemb, b0, nb);
  }

  hipLaunchKernelGGL(k_enc1, dim3(BB, 64), dim3(256), 0, stream,
                     cemb,
                     d_in[0], d_in[1], d_in[2], d_in[15], d_in[16],
                     d_in[17], d_in[18], g1);
  hipLaunchKernelGGL(k_enc2, dim3(BB, 32), dim3(256), 0, stream,
                     g1, d_in[19], d_in[20], d_in[21], d_in[22], shs, (float*)d_out);
  hipLaunchKernelGGL(k_mid,  dim3(BB, 56), dim3(256), 0, stream,
                     shs, d_in[25], d_in[26], d_in[29], d_in[30], a1s, c1s);
  hipLaunchKernelGGL(k_fin,  dim3(BB), dim3(64), 0, stream,
                     shs, a1s, c1s, d_in[23], d_in[24], d_in[27], d_in[28],
                     d_in[31], d_in[32], (float*)d_out);
}